// Round 5
// baseline (416.573 us; speedup 1.0000x reference)
//
#include <hip/hip_runtime.h>

// Problem constants (fixed by the reference)
#define N 2048
#define D 256
#define C 768          // 3*D
#define V 2
#define L 16
#define NSTATE 15      // S_0..S_14 (step-15 mask provably empty)
#define NAPP 14        // encoder applications
#define TCAP 256       // canonical masked-entry cap per variant (expected ~107)
#define FCAP 64        // follower cap per step (expected ~32)

typedef __attribute__((ext_vector_type(8))) short bf16x8;
typedef __attribute__((ext_vector_type(4))) float f32x4;

__device__ __forceinline__ ushort bf16_rn(float x) {
  unsigned u = __float_as_uint(x);
  u += 0x7FFFu + ((u >> 16) & 1u);
  return (ushort)(u >> 16);
}
__device__ __forceinline__ float bf16_f(ushort h) {
  return __uint_as_float(((unsigned)h) << 16);
}

// A chunk-tiled layout (chunk = 32 rows x 64 k = 2048 ushorts = 4 KB),
// PRE-SWIZZLED within each chunk: idx ^= (row&7)<<3 (16B-slot XOR) so that
// a linear global_load_lds copy yields a conflict-spread LDS image (rule:
// swizzle both sides or neither; writers + gemm ds_read use this same form).
__device__ __forceinline__ size_t a_addr(int row, int k) {
  size_t chunk = (size_t)(row >> 5) * 4 + (k >> 6);
  int idx = (((row & 31) * 64 + (k & 63)) ^ ((row & 7) << 3));
  return chunk * 2048 + idx;
}
// W layout: unswizzled chunked (read straight to registers in k_gemm).
__device__ __forceinline__ size_t wt_addr(int n, int k) {
  return ((size_t)(n >> 5) * 4 + (k >> 6)) * 2048 + (n & 31) * 64 + (k & 63);
}

__device__ __forceinline__ void gload16(const ushort* __restrict__ g,
                                        ushort* l) {
  __builtin_amdgcn_global_load_lds(
      (const __attribute__((address_space(1))) void*)g,
      (__attribute__((address_space(3))) void*)l, 16, 0, 0);
}

// ---------------------------------------------------------------------------
// k_init: states0 = emb; A0 bf16 split (chunked+swizzled); Wt=[W_self|W_nbr]^T
// split (chunked); zero out / fillpos.
// ---------------------------------------------------------------------------
__global__ __launch_bounds__(256) void k_init(
    const float* __restrict__ emb, const float* __restrict__ Ws,
    const float* __restrict__ Wn, float* __restrict__ states0,
    ushort* __restrict__ WtHi, ushort* __restrict__ WtLo,
    ushort* __restrict__ A0hi, ushort* __restrict__ A0lo,
    float* __restrict__ out, int* __restrict__ fillpos) {
  size_t i = (size_t)blockIdx.x * 256 + threadIdx.x;
  size_t stride = (size_t)gridDim.x * 256;
  for (size_t x = i; x < (size_t)N * D; x += stride) {
    float v = emb[x];
    states0[x] = v;
    ushort h = bf16_rn(v);
    ushort l = bf16_rn(v - bf16_f(h));
    size_t a = a_addr((int)(x >> 8), (int)(x & 255));
    A0hi[a] = h;
    A0lo[a] = l;
  }
  for (size_t x = i; x < (size_t)512 * 256; x += stride) {
    int n = (int)(x >> 8), k = (int)(x & 255);
    float v = (n < 256) ? Ws[(size_t)k * 256 + n] : Wn[(size_t)k * 256 + (n - 256)];
    ushort h = bf16_rn(v);
    size_t a = wt_addr(n, k);
    WtHi[a] = h;
    WtLo[a] = bf16_rn(v - bf16_f(h));
  }
  for (size_t x = i; x < (size_t)N * C; x += stride) out[x] = 0.f;
  for (size_t x = i; x < N; x += stride) fillpos[x] = 0;
}

// ---------------------------------------------------------------------------
// k_degA: fused k_deg (blocks 0..127) + k_metaA (blocks 128..159).
// ---------------------------------------------------------------------------
__global__ __launch_bounds__(256) void k_degA(
    const int* __restrict__ ei, int E, int* __restrict__ fillpos,
    const int* __restrict__ adj, const int* __restrict__ variants,
    int* __restrict__ stepP, int* __restrict__ stepDm,
    int* __restrict__ stepCnt, int* __restrict__ hasG, int* __restrict__ tlG) {
  __shared__ int tl_sh[16];
  __shared__ int foll[FCAP], fbits[FCAP];
  __shared__ int sh_tc, sh_fcnt, sh_ecnt;
  int t = threadIdx.x;
  if (blockIdx.x < 128) {
    for (int e = blockIdx.x * 256 + t; e < E; e += 128 * 256)
      atomicAdd(&fillpos[ei[E + e]], 1);
    return;
  }
  int vi = blockIdx.x - 128;
  int v = vi / L, i = vi % L;
  int a = variants[vi];
  if (t == 0) {
    int cnt = 0;
    for (int j = i + 1; j < L; j++) {
      int x = variants[v * L + j];
      bool dup = false;
      for (int q = 0; q < cnt; q++) if (tl_sh[q] == x) dup = true;
      if (!dup) tl_sh[cnt++] = x;
    }
    sh_tc = cnt;
    sh_fcnt = 0;
    sh_ecnt = 0;
    for (int q = 0; q < cnt; q++) tlG[vi * 16 + q] = tl_sh[q];
  }
  __syncthreads();
  for (int p = t; p < N; p += 256) {
    if (adj[(size_t)a * N + p] != 0) {
      int f = atomicAdd(&sh_fcnt, 1);
      if (f < FCAP) foll[f] = p;
    }
  }
  __syncthreads();
  int fc = sh_fcnt < FCAP ? sh_fcnt : FCAP;
  int tc = sh_tc;
  for (int x = t; x < fc; x += 256) fbits[x] = 0;
  __syncthreads();
  for (int x = t; x < fc * tc; x += 256) {
    int fi = x / tc, q = x - fi * tc;
    if (adj[(size_t)foll[fi] * N + tl_sh[q]] != 0) atomicOr(&fbits[fi], 1 << q);
  }
  __syncthreads();
  for (int fi = t; fi < fc; fi += 256) {
    int bits = fbits[fi];
    if (bits) {
      int e = atomicAdd(&sh_ecnt, 1);
      stepP[vi * FCAP + e] = foll[fi];
      stepDm[vi * FCAP + e] = bits;
    }
  }
  __syncthreads();
  if (t == 0) {
    stepCnt[vi] = sh_ecnt;
    hasG[vi] = (sh_fcnt > 0);
  }
}

// ---------------------------------------------------------------------------
// k_scan: exclusive prefix over degrees -> row_ptr; resets fillpos to starts.
// ---------------------------------------------------------------------------
__global__ __launch_bounds__(256) void k_scan(int* __restrict__ fillpos,
                                              int* __restrict__ row_ptr) {
  __shared__ int part[256];
  __shared__ int base[257];
  int t = threadIdx.x;
  int v[8];
  int s = 0;
  for (int j = 0; j < 8; j++) { v[j] = fillpos[t * 8 + j]; s += v[j]; }
  part[t] = s;
  __syncthreads();
  if (t == 0) {
    int acc = 0;
    for (int q = 0; q < 256; q++) { base[q] = acc; acc += part[q]; }
    base[256] = acc;
  }
  __syncthreads();
  int acc = base[t];
  for (int j = 0; j < 8; j++) {
    row_ptr[t * 8 + j] = acc;
    fillpos[t * 8 + j] = acc;
    acc += v[j];
  }
  if (t == 255) row_ptr[N] = base[256];
}

// ---------------------------------------------------------------------------
// k_fillB: fused k_fill (blocks 0..127) + k_metaB (blocks 128..128+V-1).
// ---------------------------------------------------------------------------
__global__ __launch_bounds__(256) void k_fillB(
    const int* __restrict__ ei, int E, int* __restrict__ fillpos,
    int* __restrict__ csr_src,
    const int* __restrict__ stepP, const int* __restrict__ stepDm,
    const int* __restrict__ stepCnt, const int* __restrict__ hasG,
    int* __restrict__ entP, int* __restrict__ entPrev, int* __restrict__ entDm,
    int* __restrict__ offsG, int* __restrict__ kidxG, int* __restrict__ cmatG,
    int* __restrict__ lastPG, int* __restrict__ lastIG, int* __restrict__ lastMG,
    int* __restrict__ cntG) {
  __shared__ int pmask[N];           // 8 KB
  __shared__ int sP[16][FCAP];       // 4 KB
  __shared__ int sDm[16][FCAP];      // 4 KB
  __shared__ int cnt[16], offs[17];
  __shared__ int cmat_sh[256];       // 1 KB
  __shared__ int sh_u;
  int t = threadIdx.x;
  if (blockIdx.x < 128) {
    for (int e = blockIdx.x * 256 + t; e < E; e += 128 * 256) {
      int dst = ei[E + e];
      int pos = atomicAdd(&fillpos[dst], 1);
      csr_src[pos] = ei[e];
    }
    return;
  }
  int v = blockIdx.x - 128;
  for (int p = t; p < N; p += 256) pmask[p] = 0;
  for (int x = t; x < 256; x += 256) cmat_sh[x] = 0;
  if (t < 16) cnt[t] = stepCnt[v * L + t];
  if (t == 0) sh_u = 0;
  __syncthreads();
  if (t == 0) {
    int acc = 0;
    for (int i = 0; i < 16; i++) {
      offs[i] = acc < TCAP ? acc : TCAP;
      acc += cnt[i];
    }
    offs[16] = acc < TCAP ? acc : TCAP;
    cntG[v * 2 + 0] = offs[16];
    int k = 0;
    for (int i = 0; i < L; i++) {
      kidxG[v * 16 + i] = k;
      if (hasG[v * L + i]) k++;
    }
  }
  for (int x = t; x < 16 * FCAP; x += 256) {
    int i = x >> 6, f = x & 63;
    if (f < stepCnt[v * L + i]) {
      int p = stepP[(v * L + i) * FCAP + f];
      sP[i][f] = p;
      sDm[i][f] = stepDm[(v * L + i) * FCAP + f];
      atomicOr(&pmask[p], 1 << i);
    }
  }
  __syncthreads();
  for (int x = t; x < 16 * FCAP; x += 256) {
    int i = x >> 6, f = x & 63;
    if (f < cnt[i]) {
      int e = offs[i] + f;
      if (e < TCAP) {
        int p = sP[i][f];
        entP[v * TCAP + e] = p;
        entDm[v * TCAP + e] = sDm[i][f];
        int m = pmask[p] & ((1 << i) - 1);
        int prev = -1;
        if (m) {
          int j = 31 - __clz(m);
          int cj = cnt[j];
          for (int f2 = 0; f2 < cj; f2++)
            if (sP[j][f2] == p) { prev = offs[j] + f2; break; }
        }
        entPrev[v * TCAP + e] = prev;
      }
    }
  }
  __syncthreads();
  for (int p = t; p < N; p += 256) {
    int m = pmask[p];
    if (m) {
      int u = atomicAdd(&sh_u, 1);
      int j = 31 - __clz(m);
      int li = -1;
      int cj = cnt[j];
      for (int f2 = 0; f2 < cj; f2++)
        if (sP[j][f2] == p) { li = offs[j] + f2; break; }
      lastPG[v * TCAP + u] = p;
      lastIG[v * TCAP + u] = li;
      lastMG[v * TCAP + u] = m;
      int mm = m;
      while (mm) {
        int bi = __ffs(mm) - 1; mm &= mm - 1;
        int m2 = m & ((1 << bi) - 1);
        while (m2) {
          int bj = __ffs(m2) - 1; m2 &= m2 - 1;
          atomicAdd(&cmat_sh[bi * 16 + bj], 1);
        }
      }
    }
  }
  __syncthreads();
  if (t == 0) cntG[v * 2 + 1] = sh_u;
  for (int x = t; x < 256; x += 256) cmatG[v * 256 + x] = cmat_sh[x];
  for (int x = t; x < 17; x += 256) offsG[v * 17 + x] = offs[x];
}

// ---------------------------------------------------------------------------
// k_gemm: Z = A @ [W_self|W_nbr]  (M=2048, K=256, N=512), bf16 3-product
// split, fp32 accum.  v2: W held in registers (64 VGPR/wave, loaded once);
// A staged via global_load_lds width=16 into linear LDS (global image is
// pre-swizzled so ds_read spreads over all 8 16B slots).  Double-buffered,
// prefetch of chunk c+1 issued before MFMA of chunk c (m97 pattern).
// ---------------------------------------------------------------------------
__global__ __launch_bounds__(256) void k_gemm(
    const ushort* __restrict__ Ah, const ushort* __restrict__ Al,
    const ushort* __restrict__ Wh_g, const ushort* __restrict__ Wl_g,
    float* __restrict__ Z) {
  __shared__ __align__(16) ushort Ash[2][2048], Asl[2][2048];  // 16 KB
  const int tid = threadIdx.x, wave = tid >> 6, lane = tid & 63;
  const int quad = lane >> 4, l16 = lane & 15;
  const int wr = wave >> 1, wc = wave & 1;
  const int mb = blockIdx.x, nb = blockIdx.y;

  // W fragments in registers: this wave's 16 output cols, full K=256.
  bf16x8 wh[8], wl[8];
  {
    const int wrow = wc * 16 + l16;
#pragma unroll
    for (int u = 0; u < 8; u++) {
      const int c = u >> 1, kf = u & 1;
      const int ko = kf * 32 + quad * 8;
      size_t idx = ((size_t)nb * 4 + c) * 2048 + wrow * 64 + ko;
      wh[u] = *(const bf16x8*)&Wh_g[idx];
      wl[u] = *(const bf16x8*)&Wl_g[idx];
    }
  }

  const size_t abase = (size_t)mb * 4 * 2048;
  // stage chunk 0 into buf 0 (each wave stages its 1KB quarter)
  gload16(&Ah[abase + tid * 8], &Ash[0][wave * 512]);
  gload16(&Al[abase + tid * 8], &Asl[0][wave * 512]);
  __syncthreads();

  f32x4 acc = {0.f, 0.f, 0.f, 0.f};
  const int arow = wr * 16 + l16;
  const int aswz = (arow & 7) << 3;
#pragma unroll
  for (int c = 0; c < 4; c++) {
    const int rb = c & 1;
    if (c < 3) {
      size_t o = abase + (size_t)(c + 1) * 2048 + tid * 8;
      gload16(&Ah[o], &Ash[rb ^ 1][wave * 512]);
      gload16(&Al[o], &Asl[rb ^ 1][wave * 512]);
    }
#pragma unroll
    for (int kf = 0; kf < 2; kf++) {
      const int ko = kf * 32 + quad * 8;
      const int aidx = (arow * 64 + ko) ^ aswz;
      bf16x8 a_h = *(const bf16x8*)&Ash[rb][aidx];
      bf16x8 a_l = *(const bf16x8*)&Asl[rb][aidx];
      const int u = c * 2 + kf;
      acc = __builtin_amdgcn_mfma_f32_16x16x32_bf16(a_h, wh[u], acc, 0, 0, 0);
      acc = __builtin_amdgcn_mfma_f32_16x16x32_bf16(a_h, wl[u], acc, 0, 0, 0);
      acc = __builtin_amdgcn_mfma_f32_16x16x32_bf16(a_l, wh[u], acc, 0, 0, 0);
    }
    if (c < 3) __syncthreads();
  }
  const int col = nb * 32 + wc * 16 + l16;
  const int row0 = mb * 32 + wr * 16 + quad * 4;
#pragma unroll
  for (int r = 0; r < 4; r++)
    Z[(size_t)(row0 + r) * 512 + col] = acc[r];
}

// ---------------------------------------------------------------------------
// k_comb: next[r] = relu(Z1[r] + sum_{e in in(r)} Z2[src_e] + b).
// One wave per row; 4-way unrolled gather.  Writes states fp32 + bf16 split
// of next A (chunked+swizzled).  (validated R4)
// ---------------------------------------------------------------------------
__global__ __launch_bounds__(256) void k_comb(
    const float* __restrict__ Z, const float* __restrict__ bias,
    const int* __restrict__ row_ptr, const int* __restrict__ csr_src,
    float* __restrict__ stnext, ushort* __restrict__ NAh,
    ushort* __restrict__ NAl) {
  int row = blockIdx.x * 4 + (threadIdx.x >> 6);
  int lane = threadIdx.x & 63;
  const float4* Zp = (const float4*)Z;
  float4 acc = Zp[(size_t)row * 128 + lane];            // Z1 self
  float4 acc2 = {0.f, 0.f, 0.f, 0.f};
  float4 acc3 = {0.f, 0.f, 0.f, 0.f};
  float4 acc4 = {0.f, 0.f, 0.f, 0.f};
  int e0 = row_ptr[row], e1 = row_ptr[row + 1];
  int e = e0;
  for (; e + 3 < e1; e += 4) {
    int s0 = csr_src[e], s1 = csr_src[e + 1];
    int s2 = csr_src[e + 2], s3 = csr_src[e + 3];
    float4 x0 = Zp[(size_t)s0 * 128 + 64 + lane];
    float4 x1 = Zp[(size_t)s1 * 128 + 64 + lane];
    float4 x2 = Zp[(size_t)s2 * 128 + 64 + lane];
    float4 x3 = Zp[(size_t)s3 * 128 + 64 + lane];
    acc.x += x0.x; acc.y += x0.y; acc.z += x0.z; acc.w += x0.w;
    acc2.x += x1.x; acc2.y += x1.y; acc2.z += x1.z; acc2.w += x1.w;
    acc3.x += x2.x; acc3.y += x2.y; acc3.z += x2.z; acc3.w += x2.w;
    acc4.x += x3.x; acc4.y += x3.y; acc4.z += x3.z; acc4.w += x3.w;
  }
  for (; e < e1; e++) {
    float4 x0 = Zp[(size_t)csr_src[e] * 128 + 64 + lane];
    acc.x += x0.x; acc.y += x0.y; acc.z += x0.z; acc.w += x0.w;
  }
  float4 bv = ((const float4*)bias)[lane];
  float v0 = fmaxf(acc.x + acc2.x + acc3.x + acc4.x + bv.x, 0.f);
  float v1 = fmaxf(acc.y + acc2.y + acc3.y + acc4.y + bv.y, 0.f);
  float v2 = fmaxf(acc.z + acc2.z + acc3.z + acc4.z + bv.z, 0.f);
  float v3 = fmaxf(acc.w + acc2.w + acc3.w + acc4.w + bv.w, 0.f);
  *(float4*)(stnext + (size_t)row * D + lane * 4) = make_float4(v0, v1, v2, v3);
  ushort h0 = bf16_rn(v0), h1 = bf16_rn(v1), h2 = bf16_rn(v2), h3 = bf16_rn(v3);
  size_t ca = a_addr(row, lane * 4);
  *(ushort4*)&NAh[ca] = make_ushort4(h0, h1, h2, h3);
  *(ushort4*)&NAl[ca] = make_ushort4(
      bf16_rn(v0 - bf16_f(h0)), bf16_rn(v1 - bf16_f(h1)),
      bf16_rn(v2 - bf16_f(h2)), bf16_rn(v3 - bf16_f(h3)));
}

// ---------------------------------------------------------------------------
// k_pi: LINEAR reformulation, 256 threads/block (4 waves).  (validated R2-R4)
// ---------------------------------------------------------------------------
#define PI_LDS_BYTES (TCAP * 64 * 4 + 16 * 64 * 4 + 16 * 64 * 4 + 256 * 4 + \
                      3 * TCAP * 4 + 17 * 4 + 16 * 4 + 256 * 4)
__global__ __launch_bounds__(256) void k_pi(
    const float* __restrict__ states, float* __restrict__ out,
    const int* __restrict__ variants,
    const int* __restrict__ entP, const int* __restrict__ entPrev,
    const int* __restrict__ entDm, const int* __restrict__ offsG,
    const int* __restrict__ kidxG, const int* __restrict__ tlG,
    const int* __restrict__ cmatG, const int* __restrict__ lastPG,
    const int* __restrict__ lastIG, const int* __restrict__ lastMG,
    const int* __restrict__ cntG) {
  extern __shared__ __align__(16) float smf[];
  float* catb = smf;                       // [TCAP][64]  (becomes pref)
  float* S_lds = catb + TCAP * 64;         // [16][64]
  float* aS = S_lds + 16 * 64;             // [16][64] per-step sums
  float* cmatf = aS + 16 * 64;             // [256]
  int* eP  = (int*)(cmatf + 256);          // [TCAP]
  int* ePr = eP + TCAP;
  int* eDm = ePr + TCAP;
  int* offs = eDm + TCAP;                  // [17]
  int* kidx = offs + 17;                   // [16]
  int* tl = kidx + 16;                     // [256]
  int v = blockIdx.x / 12, cgi = blockIdx.x % 12;
  int grp = cgi >> 2;
  int tid = threadIdx.x, lane = tid & 63, w = tid >> 6;
  int cl = (cgi & 3) * 64 + lane;          // 0..255 within third
  int col = cgi * 64 + lane;               // 0..767

  int T = cntG[v * 2 + 0], U = cntG[v * 2 + 1];
  for (int x = tid; x < T; x += 256) {
    eP[x] = entP[v * TCAP + x];
    ePr[x] = entPrev[v * TCAP + x];
    eDm[x] = entDm[v * TCAP + x];
  }
  for (int x = tid; x < 17; x += 256) offs[x] = offsG[v * 17 + x];
  if (tid < 16) kidx[tid] = kidxG[v * 16 + tid];
  for (int x = tid; x < 256; x += 256) {
    tl[x] = tlG[v * 256 + x];
    cmatf[x] = (float)cmatG[v * 256 + x];
  }
  __syncthreads();

  // cat fill: waves split the entries of each step
  for (int i = 0; i < L; i++) {
    int kk = kidx[i]; if (kk > NSTATE - 1) kk = NSTATE - 1;
    const float* embS = states + (size_t)kk * N * D;
    int o0 = offs[i], o1 = offs[i + 1];
    if (grp == 0) {
      for (int e = o0 + w; e < o1; e += 4)
        catb[e * 64 + lane] = embS[(size_t)eP[e] * D + cl];
    } else if (grp == 1) {
      float embA = embS[(size_t)variants[v * L + i] * D + cl];
      for (int e = o0 + w; e < o1; e += 4) catb[e * 64 + lane] = embA;
    } else {
      for (int e = o0 + w; e < o1; e += 4) {
        float sa = 0.f;
        int bm = eDm[e];
        while (bm) {
          int q = __ffs(bm) - 1; bm &= bm - 1;
          sa += embS[(size_t)tl[i * 16 + q] * D + cl];
        }
        catb[e * 64 + lane] = sa;
      }
    }
  }
  __syncthreads();
  // prefix over place-chains, chains distributed across waves
  for (int u = w; u < U; u += 4) {
    int li = lastIG[v * TCAP + u];
    int len = 0;
    for (int c2 = li; c2 >= 0; c2 = ePr[c2]) len++;
    for (int j = 1; j < len; j++) {        // root -> last order
      int c2 = li;
      for (int k = 0; k < len - 1 - j; k++) c2 = ePr[c2];
      catb[c2 * 64 + lane] += catb[ePr[c2] * 64 + lane];
    }
  }
  __syncthreads();
  // per-step sums of pref
  for (int i = w; i < 16; i += 4) {
    float a = 0.f;
    for (int e = offs[i]; e < offs[i + 1]; e++) a += catb[e * 64 + lane];
    aS[i * 64 + lane] = a;
  }
  __syncthreads();
  // S recurrence (serial over 16 steps, wave 0)
  if (w == 0) {
    float S[16];
    float Sp = 0.f;
#pragma unroll
    for (int i = 0; i < 16; i++) {
      float sv = Sp + aS[i * 64 + lane];
#pragma unroll
      for (int j = 0; j < 16; j++)
        if (j < i) sv += cmatf[i * 16 + j] * S[j];
      S[i] = sv;
      S_lds[i * 64 + lane] = sv;
      Sp = sv;
    }
  }
  __syncthreads();
  // outputs, places distributed across waves
  for (int u = w; u < U; u += 4) {
    int p = lastPG[v * TCAP + u];
    int li = lastIG[v * TCAP + u];
    int m = lastMG[v * TCAP + u];
    float acc = catb[li * 64 + lane];
    while (m) {
      int q = __ffs(m) - 1; m &= m - 1;
      acc += S_lds[q * 64 + lane];
    }
    atomicAdd(&out[(size_t)p * C + col], acc);
  }
}

// ---------------------------------------------------------------------------
extern "C" void kernel_launch(void* const* d_in, const int* in_sizes, int n_in,
                              void* d_out, int out_size, void* d_ws, size_t ws_size,
                              hipStream_t stream) {
  const float* emb      = (const float*)d_in[0];
  const float* Ws       = (const float*)d_in[1];
  const float* Wn       = (const float*)d_in[2];
  const float* bias     = (const float*)d_in[3];
  const int*   variants = (const int*)d_in[4];
  const int*   adj      = (const int*)d_in[5];
  const int*   ei       = (const int*)d_in[6];
  const int    E        = in_sizes[6] / 2;
  float* out            = (float*)d_out;

  char* base = (char*)d_ws;
  float* states = (float*)base;            base += (size_t)NSTATE * N * D * 4;
  float* Z      = (float*)base;            base += (size_t)N * 512 * 4;
  ushort* WtHi  = (ushort*)base;           base += (size_t)512 * 256 * 2;
  ushort* WtLo  = (ushort*)base;           base += (size_t)512 * 256 * 2;
  ushort* A0h   = (ushort*)base;           base += (size_t)N * D * 2;
  ushort* A0l   = (ushort*)base;           base += (size_t)N * D * 2;
  ushort* A1h   = (ushort*)base;           base += (size_t)N * D * 2;
  ushort* A1l   = (ushort*)base;           base += (size_t)N * D * 2;
  int* row_ptr  = (int*)base;              base += (N + 1) * 4;
  int* fillpos  = (int*)base;              base += N * 4;
  int* csr_src  = (int*)base;              base += (size_t)E * 4;
  int* stepP    = (int*)base;              base += V * L * FCAP * 4;
  int* stepDm   = (int*)base;              base += V * L * FCAP * 4;
  int* stepCnt  = (int*)base;              base += V * L * 4;
  int* hasG     = (int*)base;              base += V * L * 4;
  int* entP     = (int*)base;              base += V * TCAP * 4;
  int* entPrev  = (int*)base;              base += V * TCAP * 4;
  int* entDm    = (int*)base;              base += V * TCAP * 4;
  int* offsG    = (int*)base;              base += V * 17 * 4;
  int* kidxG    = (int*)base;              base += V * 16 * 4;
  int* tlG      = (int*)base;              base += V * 256 * 4;
  int* cmatG    = (int*)base;              base += V * 256 * 4;
  int* lastPG   = (int*)base;              base += V * TCAP * 4;
  int* lastIG   = (int*)base;              base += V * TCAP * 4;
  int* lastMG   = (int*)base;              base += V * TCAP * 4;
  int* cntG     = (int*)base;              base += V * 2 * 4;

  hipFuncSetAttribute((const void*)k_pi,
                      hipFuncAttributeMaxDynamicSharedMemorySize, PI_LDS_BYTES);

  k_init<<<512, 256, 0, stream>>>(emb, Ws, Wn, states, WtHi, WtLo, A0h, A0l,
                                  out, fillpos);
  k_degA<<<128 + V * L, 256, 0, stream>>>(ei, E, fillpos, adj, variants,
                                          stepP, stepDm, stepCnt, hasG, tlG);
  k_scan<<<1, 256, 0, stream>>>(fillpos, row_ptr);
  k_fillB<<<128 + V, 256, 0, stream>>>(ei, E, fillpos, csr_src, stepP, stepDm,
                                       stepCnt, hasG, entP, entPrev, entDm,
                                       offsG, kidxG, cmatG, lastPG, lastIG,
                                       lastMG, cntG);

  ushort* AH[2] = {A0h, A1h};
  ushort* AL[2] = {A0l, A1l};
  for (int s = 0; s < NAPP; s++) {
    int cur = s & 1, nxt = cur ^ 1;
    k_gemm<<<dim3(64, 16), 256, 0, stream>>>(AH[cur], AL[cur], WtHi, WtLo, Z);
    k_comb<<<N / 4, 256, 0, stream>>>(Z, bias, row_ptr, csr_src,
                                      states + (size_t)(s + 1) * N * D,
                                      AH[nxt], AL[nxt]);
  }
  k_pi<<<V * 12, 256, PI_LDS_BYTES, stream>>>(states, out, variants, entP,
                                              entPrev, entDm, offsG, kidxG, tlG,
                                              cmatG, lastPG, lastIG, lastMG,
                                              cntG);
}

// Round 6
// 366.314 us; speedup vs baseline: 1.1372x; 1.1372x over previous
//
#include <hip/hip_runtime.h>

// Problem constants (fixed by the reference)
#define N 2048
#define D 256
#define C 768          // 3*D
#define V 2
#define L 16
#define NSTATE 15      // S_0..S_14 (step-15 mask provably empty)
#define NAPP 14        // encoder applications
#define TCAP 256       // canonical masked-entry cap per variant (expected ~107)
#define FCAP 64        // follower cap per step (expected ~32)

typedef __attribute__((ext_vector_type(8))) short bf16x8;
typedef __attribute__((ext_vector_type(4))) float f32x4;

__device__ __forceinline__ ushort bf16_rn(float x) {
  unsigned u = __float_as_uint(x);
  u += 0x7FFFu + ((u >> 16) & 1u);
  return (ushort)(u >> 16);
}
__device__ __forceinline__ float bf16_f(ushort h) {
  return __uint_as_float(((unsigned)h) << 16);
}

// Chunk-tiled operand layouts (chunk = 32 rows x 64 k = 2048 ushorts = 4 KB).
// (R4-validated, unswizzled)
__device__ __forceinline__ size_t a_addr(int row, int k) {
  return ((size_t)(row >> 5) * 4 + (k >> 6)) * 2048 + (row & 31) * 64 + (k & 63);
}
__device__ __forceinline__ size_t wt_addr(int n, int k) {
  return ((size_t)(n >> 5) * 4 + (k >> 6)) * 2048 + (n & 31) * 64 + (k & 63);
}

// ---------------------------------------------------------------------------
// k_init: blocks 0..511: states0 = emb; A0 bf16 split (chunked);
// Wt=[W_self|W_nbr]^T split (chunked); zero out.
// blocks 512..543: metaA (per (variant,step) follower lists + dest bitmasks).
// fillpos is no longer pre-zeroed (k_scan builds the histogram itself).
// ---------------------------------------------------------------------------
__global__ __launch_bounds__(256) void k_init(
    const float* __restrict__ emb, const float* __restrict__ Ws,
    const float* __restrict__ Wn, float* __restrict__ states0,
    ushort* __restrict__ WtHi, ushort* __restrict__ WtLo,
    ushort* __restrict__ A0hi, ushort* __restrict__ A0lo,
    float* __restrict__ out,
    const int* __restrict__ adj, const int* __restrict__ variants,
    int* __restrict__ stepP, int* __restrict__ stepDm,
    int* __restrict__ stepCnt, int* __restrict__ hasG, int* __restrict__ tlG) {
  __shared__ int tl_sh[16];
  __shared__ int foll[FCAP], fbits[FCAP];
  __shared__ int sh_tc, sh_fcnt, sh_ecnt;
  int t = threadIdx.x;
  if (blockIdx.x < 512) {
    size_t i = (size_t)blockIdx.x * 256 + t;
    const size_t stride = (size_t)512 * 256;
    for (size_t x = i; x < (size_t)N * D; x += stride) {
      float v = emb[x];
      states0[x] = v;
      ushort h = bf16_rn(v);
      ushort l = bf16_rn(v - bf16_f(h));
      size_t a = a_addr((int)(x >> 8), (int)(x & 255));
      A0hi[a] = h;
      A0lo[a] = l;
    }
    for (size_t x = i; x < (size_t)512 * 256; x += stride) {
      int n = (int)(x >> 8), k = (int)(x & 255);
      float v = (n < 256) ? Ws[(size_t)k * 256 + n]
                          : Wn[(size_t)k * 256 + (n - 256)];
      ushort h = bf16_rn(v);
      size_t a = wt_addr(n, k);
      WtHi[a] = h;
      WtLo[a] = bf16_rn(v - bf16_f(h));
    }
    for (size_t x = i; x < (size_t)N * C; x += stride) out[x] = 0.f;
    return;
  }
  // ---- metaA (was k_degA blocks 128..159) ----
  int vi = blockIdx.x - 512;
  int v = vi / L, i = vi % L;
  int a = variants[vi];
  if (t == 0) {
    int cnt = 0;
    for (int j = i + 1; j < L; j++) {
      int x = variants[v * L + j];
      bool dup = false;
      for (int q = 0; q < cnt; q++) if (tl_sh[q] == x) dup = true;
      if (!dup) tl_sh[cnt++] = x;
    }
    sh_tc = cnt;
    sh_fcnt = 0;
    sh_ecnt = 0;
    for (int q = 0; q < cnt; q++) tlG[vi * 16 + q] = tl_sh[q];
  }
  __syncthreads();
  for (int p = t; p < N; p += 256) {
    if (adj[(size_t)a * N + p] != 0) {
      int f = atomicAdd(&sh_fcnt, 1);
      if (f < FCAP) foll[f] = p;
    }
  }
  __syncthreads();
  int fc = sh_fcnt < FCAP ? sh_fcnt : FCAP;
  int tc = sh_tc;
  for (int x = t; x < fc; x += 256) fbits[x] = 0;
  __syncthreads();
  for (int x = t; x < fc * tc; x += 256) {
    int fi = x / tc, q = x - fi * tc;
    if (adj[(size_t)foll[fi] * N + tl_sh[q]] != 0) atomicOr(&fbits[fi], 1 << q);
  }
  __syncthreads();
  for (int fi = t; fi < fc; fi += 256) {
    int bits = fbits[fi];
    if (bits) {
      int e = atomicAdd(&sh_ecnt, 1);
      stepP[vi * FCAP + e] = foll[fi];
      stepDm[vi * FCAP + e] = bits;
    }
  }
  __syncthreads();
  if (t == 0) {
    stepCnt[vi] = sh_ecnt;
    hasG[vi] = (sh_fcnt > 0);
  }
}

// ---------------------------------------------------------------------------
// k_scan: LDS histogram over edge destinations + exclusive prefix ->
// row_ptr; writes fillpos = start offsets (for k_fillB's scatter).
// One block; replaces the old 128-block atomic deg pass entirely.
// ---------------------------------------------------------------------------
__global__ __launch_bounds__(256) void k_scan(const int* __restrict__ ei,
                                              int E, int* __restrict__ fillpos,
                                              int* __restrict__ row_ptr) {
  __shared__ int hist[N];            // 8 KB
  __shared__ int part[256];
  __shared__ int base[257];
  int t = threadIdx.x;
  for (int p = t; p < N; p += 256) hist[p] = 0;
  __syncthreads();
  for (int e = t; e < E; e += 256) atomicAdd(&hist[ei[E + e]], 1);
  __syncthreads();
  int v[8];
  int s = 0;
  for (int j = 0; j < 8; j++) { v[j] = hist[t * 8 + j]; s += v[j]; }
  part[t] = s;
  __syncthreads();
  if (t == 0) {
    int acc = 0;
    for (int q = 0; q < 256; q++) { base[q] = acc; acc += part[q]; }
    base[256] = acc;
  }
  __syncthreads();
  int acc = base[t];
  for (int j = 0; j < 8; j++) {
    row_ptr[t * 8 + j] = acc;
    fillpos[t * 8 + j] = acc;
    acc += v[j];
  }
  if (t == 255) row_ptr[N] = base[256];
}

// ---------------------------------------------------------------------------
// k_fillB: fused k_fill (blocks 0..127) + k_metaB (blocks 128..128+V-1).
// ---------------------------------------------------------------------------
__global__ __launch_bounds__(256) void k_fillB(
    const int* __restrict__ ei, int E, int* __restrict__ fillpos,
    int* __restrict__ csr_src,
    const int* __restrict__ stepP, const int* __restrict__ stepDm,
    const int* __restrict__ stepCnt, const int* __restrict__ hasG,
    int* __restrict__ entP, int* __restrict__ entPrev, int* __restrict__ entDm,
    int* __restrict__ offsG, int* __restrict__ kidxG, int* __restrict__ cmatG,
    int* __restrict__ lastPG, int* __restrict__ lastIG, int* __restrict__ lastMG,
    int* __restrict__ cntG) {
  __shared__ int pmask[N];           // 8 KB
  __shared__ int sP[16][FCAP];       // 4 KB
  __shared__ int sDm[16][FCAP];      // 4 KB
  __shared__ int cnt[16], offs[17];
  __shared__ int cmat_sh[256];       // 1 KB
  __shared__ int sh_u;
  int t = threadIdx.x;
  if (blockIdx.x < 128) {
    for (int e = blockIdx.x * 256 + t; e < E; e += 128 * 256) {
      int dst = ei[E + e];
      int pos = atomicAdd(&fillpos[dst], 1);
      csr_src[pos] = ei[e];
    }
    return;
  }
  int v = blockIdx.x - 128;
  for (int p = t; p < N; p += 256) pmask[p] = 0;
  for (int x = t; x < 256; x += 256) cmat_sh[x] = 0;
  if (t < 16) cnt[t] = stepCnt[v * L + t];
  if (t == 0) sh_u = 0;
  __syncthreads();
  if (t == 0) {
    int acc = 0;
    for (int i = 0; i < 16; i++) {
      offs[i] = acc < TCAP ? acc : TCAP;
      acc += cnt[i];
    }
    offs[16] = acc < TCAP ? acc : TCAP;
    cntG[v * 2 + 0] = offs[16];
    int k = 0;
    for (int i = 0; i < L; i++) {
      kidxG[v * 16 + i] = k;
      if (hasG[v * L + i]) k++;
    }
  }
  for (int x = t; x < 16 * FCAP; x += 256) {
    int i = x >> 6, f = x & 63;
    if (f < stepCnt[v * L + i]) {
      int p = stepP[(v * L + i) * FCAP + f];
      sP[i][f] = p;
      sDm[i][f] = stepDm[(v * L + i) * FCAP + f];
      atomicOr(&pmask[p], 1 << i);
    }
  }
  __syncthreads();
  for (int x = t; x < 16 * FCAP; x += 256) {
    int i = x >> 6, f = x & 63;
    if (f < cnt[i]) {
      int e = offs[i] + f;
      if (e < TCAP) {
        int p = sP[i][f];
        entP[v * TCAP + e] = p;
        entDm[v * TCAP + e] = sDm[i][f];
        int m = pmask[p] & ((1 << i) - 1);
        int prev = -1;
        if (m) {
          int j = 31 - __clz(m);
          int cj = cnt[j];
          for (int f2 = 0; f2 < cj; f2++)
            if (sP[j][f2] == p) { prev = offs[j] + f2; break; }
        }
        entPrev[v * TCAP + e] = prev;
      }
    }
  }
  __syncthreads();
  for (int p = t; p < N; p += 256) {
    int m = pmask[p];
    if (m) {
      int u = atomicAdd(&sh_u, 1);
      int j = 31 - __clz(m);
      int li = -1;
      int cj = cnt[j];
      for (int f2 = 0; f2 < cj; f2++)
        if (sP[j][f2] == p) { li = offs[j] + f2; break; }
      lastPG[v * TCAP + u] = p;
      lastIG[v * TCAP + u] = li;
      lastMG[v * TCAP + u] = m;
      int mm = m;
      while (mm) {
        int bi = __ffs(mm) - 1; mm &= mm - 1;
        int m2 = m & ((1 << bi) - 1);
        while (m2) {
          int bj = __ffs(m2) - 1; m2 &= m2 - 1;
          atomicAdd(&cmat_sh[bi * 16 + bj], 1);
        }
      }
    }
  }
  __syncthreads();
  if (t == 0) cntG[v * 2 + 1] = sh_u;
  for (int x = t; x < 256; x += 256) cmatG[v * 256 + x] = cmat_sh[x];
  for (int x = t; x < 17; x += 256) offsG[v * 17 + x] = offs[x];
}

// ---------------------------------------------------------------------------
// k_gemm: Z = A @ [W_self|W_nbr]  (M=2048, K=256, N=512), bf16 3-product
// split, fp32 accum.  LDS double-buffered; global prefetch of chunk c+1
// overlaps MFMA of chunk c.  (R4-validated; R5's reg-W/gload_lds variant
// regressed -- do not touch.)
// ---------------------------------------------------------------------------
__global__ __launch_bounds__(256) void k_gemm(
    const ushort* __restrict__ Ah, const ushort* __restrict__ Al,
    const ushort* __restrict__ Wh_g, const ushort* __restrict__ Wl_g,
    float* __restrict__ Z) {
  __shared__ __align__(16) ushort Ash[2][32][72], Asl[2][32][72];
  __shared__ __align__(16) ushort Wsh[2][32][72], Wsl[2][32][72];
  const int tid = threadIdx.x, wave = tid >> 6, lane = tid & 63;
  const int quad = lane >> 4, l16 = lane & 15;
  const int wr = wave >> 1, wc = wave & 1;
  const int mb = blockIdx.x, nb = blockIdx.y;
  const int sr = tid >> 3, sc = (tid & 7) * 8;

  f32x4 acc = {0.f, 0.f, 0.f, 0.f};
  size_t abase = (size_t)mb * 4 * 2048 + (size_t)tid * 8;
  size_t wbase = (size_t)nb * 4 * 2048 + (size_t)tid * 8;
  // stage chunk 0 into buf 0
  {
    uint4 ra  = *(const uint4*)&Ah[abase];
    uint4 rl  = *(const uint4*)&Al[abase];
    uint4 rwh = *(const uint4*)&Wh_g[wbase];
    uint4 rwl = *(const uint4*)&Wl_g[wbase];
    *(uint4*)&Ash[0][sr][sc] = ra;
    *(uint4*)&Asl[0][sr][sc] = rl;
    *(uint4*)&Wsh[0][sr][sc] = rwh;
    *(uint4*)&Wsl[0][sr][sc] = rwl;
  }
  __syncthreads();
#pragma unroll
  for (int c = 0; c < 4; c++) {
    const int rb = c & 1;
    uint4 ra, rl, rwh, rwl;
    if (c < 3) {
      size_t o = (size_t)(c + 1) * 2048;
      ra  = *(const uint4*)&Ah[abase + o];
      rl  = *(const uint4*)&Al[abase + o];
      rwh = *(const uint4*)&Wh_g[wbase + o];
      rwl = *(const uint4*)&Wl_g[wbase + o];
    }
#pragma unroll
    for (int kf = 0; kf < 2; kf++) {
      int ko = kf * 32 + quad * 8;
      bf16x8 a_h = *(const bf16x8*)&Ash[rb][wr * 16 + l16][ko];
      bf16x8 a_l = *(const bf16x8*)&Asl[rb][wr * 16 + l16][ko];
      bf16x8 w_h = *(const bf16x8*)&Wsh[rb][wc * 16 + l16][ko];
      bf16x8 w_l = *(const bf16x8*)&Wsl[rb][wc * 16 + l16][ko];
      acc = __builtin_amdgcn_mfma_f32_16x16x32_bf16(a_h, w_h, acc, 0, 0, 0);
      acc = __builtin_amdgcn_mfma_f32_16x16x32_bf16(a_h, w_l, acc, 0, 0, 0);
      acc = __builtin_amdgcn_mfma_f32_16x16x32_bf16(a_l, w_h, acc, 0, 0, 0);
    }
    if (c < 3) {
      const int wb = rb ^ 1;
      *(uint4*)&Ash[wb][sr][sc] = ra;
      *(uint4*)&Asl[wb][sr][sc] = rl;
      *(uint4*)&Wsh[wb][sr][sc] = rwh;
      *(uint4*)&Wsl[wb][sr][sc] = rwl;
      __syncthreads();
    }
  }
  int col = nb * 32 + wc * 16 + l16;
  int row0 = mb * 32 + wr * 16 + quad * 4;
#pragma unroll
  for (int r = 0; r < 4; r++)
    Z[(size_t)(row0 + r) * 512 + col] = acc[r];
}

// ---------------------------------------------------------------------------
// k_comb: next[r] = relu(Z1[r] + sum_{e in in(r)} Z2[src_e] + b).
// One wave per row; 4-way unrolled gather.  (R4-validated)
// ---------------------------------------------------------------------------
__global__ __launch_bounds__(256) void k_comb(
    const float* __restrict__ Z, const float* __restrict__ bias,
    const int* __restrict__ row_ptr, const int* __restrict__ csr_src,
    float* __restrict__ stnext, ushort* __restrict__ NAh,
    ushort* __restrict__ NAl) {
  int row = blockIdx.x * 4 + (threadIdx.x >> 6);
  int lane = threadIdx.x & 63;
  const float4* Zp = (const float4*)Z;
  float4 acc = Zp[(size_t)row * 128 + lane];            // Z1 self
  float4 acc2 = {0.f, 0.f, 0.f, 0.f};
  float4 acc3 = {0.f, 0.f, 0.f, 0.f};
  float4 acc4 = {0.f, 0.f, 0.f, 0.f};
  int e0 = row_ptr[row], e1 = row_ptr[row + 1];
  int e = e0;
  for (; e + 3 < e1; e += 4) {
    int s0 = csr_src[e], s1 = csr_src[e + 1];
    int s2 = csr_src[e + 2], s3 = csr_src[e + 3];
    float4 x0 = Zp[(size_t)s0 * 128 + 64 + lane];
    float4 x1 = Zp[(size_t)s1 * 128 + 64 + lane];
    float4 x2 = Zp[(size_t)s2 * 128 + 64 + lane];
    float4 x3 = Zp[(size_t)s3 * 128 + 64 + lane];
    acc.x += x0.x; acc.y += x0.y; acc.z += x0.z; acc.w += x0.w;
    acc2.x += x1.x; acc2.y += x1.y; acc2.z += x1.z; acc2.w += x1.w;
    acc3.x += x2.x; acc3.y += x2.y; acc3.z += x2.z; acc3.w += x2.w;
    acc4.x += x3.x; acc4.y += x3.y; acc4.z += x3.z; acc4.w += x3.w;
  }
  for (; e < e1; e++) {
    float4 x0 = Zp[(size_t)csr_src[e] * 128 + 64 + lane];
    acc.x += x0.x; acc.y += x0.y; acc.z += x0.z; acc.w += x0.w;
  }
  float4 bv = ((const float4*)bias)[lane];
  float v0 = fmaxf(acc.x + acc2.x + acc3.x + acc4.x + bv.x, 0.f);
  float v1 = fmaxf(acc.y + acc2.y + acc3.y + acc4.y + bv.y, 0.f);
  float v2 = fmaxf(acc.z + acc2.z + acc3.z + acc4.z + bv.z, 0.f);
  float v3 = fmaxf(acc.w + acc2.w + acc3.w + acc4.w + bv.w, 0.f);
  *(float4*)(stnext + (size_t)row * D + lane * 4) = make_float4(v0, v1, v2, v3);
  ushort h0 = bf16_rn(v0), h1 = bf16_rn(v1), h2 = bf16_rn(v2), h3 = bf16_rn(v3);
  size_t ca = a_addr(row, lane * 4);
  *(ushort4*)&NAh[ca] = make_ushort4(h0, h1, h2, h3);
  *(ushort4*)&NAl[ca] = make_ushort4(
      bf16_rn(v0 - bf16_f(h0)), bf16_rn(v1 - bf16_f(h1)),
      bf16_rn(v2 - bf16_f(h2)), bf16_rn(v3 - bf16_f(h3)));
}

// ---------------------------------------------------------------------------
// k_pi: LINEAR reformulation, now 512 threads/block (8 waves; was 4).
// All parallel phases stride 8; only the 16-step S recurrence stays on
// wave 0.  LDS unchanged (1 block/CU either way -> 2 waves/SIMD now).
// ---------------------------------------------------------------------------
#define PI_LDS_BYTES (TCAP * 64 * 4 + 16 * 64 * 4 + 16 * 64 * 4 + 256 * 4 + \
                      3 * TCAP * 4 + 17 * 4 + 16 * 4 + 256 * 4)
__global__ __launch_bounds__(512) void k_pi(
    const float* __restrict__ states, float* __restrict__ out,
    const int* __restrict__ variants,
    const int* __restrict__ entP, const int* __restrict__ entPrev,
    const int* __restrict__ entDm, const int* __restrict__ offsG,
    const int* __restrict__ kidxG, const int* __restrict__ tlG,
    const int* __restrict__ cmatG, const int* __restrict__ lastPG,
    const int* __restrict__ lastIG, const int* __restrict__ lastMG,
    const int* __restrict__ cntG) {
  extern __shared__ __align__(16) float smf[];
  float* catb = smf;                       // [TCAP][64]  (becomes pref)
  float* S_lds = catb + TCAP * 64;         // [16][64]
  float* aS = S_lds + 16 * 64;             // [16][64] per-step sums
  float* cmatf = aS + 16 * 64;             // [256]
  int* eP  = (int*)(cmatf + 256);          // [TCAP]
  int* ePr = eP + TCAP;
  int* eDm = ePr + TCAP;
  int* offs = eDm + TCAP;                  // [17]
  int* kidx = offs + 17;                   // [16]
  int* tl = kidx + 16;                     // [256]
  int v = blockIdx.x / 12, cgi = blockIdx.x % 12;
  int grp = cgi >> 2;
  int tid = threadIdx.x, lane = tid & 63, w = tid >> 6;   // w in 0..7
  int cl = (cgi & 3) * 64 + lane;          // 0..255 within third
  int col = cgi * 64 + lane;               // 0..767

  int T = cntG[v * 2 + 0], U = cntG[v * 2 + 1];
  for (int x = tid; x < T; x += 512) {
    eP[x] = entP[v * TCAP + x];
    ePr[x] = entPrev[v * TCAP + x];
    eDm[x] = entDm[v * TCAP + x];
  }
  for (int x = tid; x < 17; x += 512) offs[x] = offsG[v * 17 + x];
  if (tid < 16) kidx[tid] = kidxG[v * 16 + tid];
  for (int x = tid; x < 256; x += 512) {
    tl[x] = tlG[v * 256 + x];
    cmatf[x] = (float)cmatG[v * 256 + x];
  }
  __syncthreads();

  // cat fill: 8 waves split the entries of each step
  for (int i = 0; i < L; i++) {
    int kk = kidx[i]; if (kk > NSTATE - 1) kk = NSTATE - 1;
    const float* embS = states + (size_t)kk * N * D;
    int o0 = offs[i], o1 = offs[i + 1];
    if (grp == 0) {
      for (int e = o0 + w; e < o1; e += 8)
        catb[e * 64 + lane] = embS[(size_t)eP[e] * D + cl];
    } else if (grp == 1) {
      float embA = embS[(size_t)variants[v * L + i] * D + cl];
      for (int e = o0 + w; e < o1; e += 8) catb[e * 64 + lane] = embA;
    } else {
      for (int e = o0 + w; e < o1; e += 8) {
        float sa = 0.f;
        int bm = eDm[e];
        while (bm) {
          int q = __ffs(bm) - 1; bm &= bm - 1;
          sa += embS[(size_t)tl[i * 16 + q] * D + cl];
        }
        catb[e * 64 + lane] = sa;
      }
    }
  }
  __syncthreads();
  // prefix over place-chains, chains distributed across 8 waves
  for (int u = w; u < U; u += 8) {
    int li = lastIG[v * TCAP + u];
    int len = 0;
    for (int c2 = li; c2 >= 0; c2 = ePr[c2]) len++;
    for (int j = 1; j < len; j++) {        // root -> last order
      int c2 = li;
      for (int k = 0; k < len - 1 - j; k++) c2 = ePr[c2];
      catb[c2 * 64 + lane] += catb[ePr[c2] * 64 + lane];
    }
  }
  __syncthreads();
  // per-step sums of pref
  for (int i = w; i < 16; i += 8) {
    float a = 0.f;
    for (int e = offs[i]; e < offs[i + 1]; e++) a += catb[e * 64 + lane];
    aS[i * 64 + lane] = a;
  }
  __syncthreads();
  // S recurrence (serial over 16 steps, wave 0)
  if (w == 0) {
    float S[16];
    float Sp = 0.f;
#pragma unroll
    for (int i = 0; i < 16; i++) {
      float sv = Sp + aS[i * 64 + lane];
#pragma unroll
      for (int j = 0; j < 16; j++)
        if (j < i) sv += cmatf[i * 16 + j] * S[j];
      S[i] = sv;
      S_lds[i * 64 + lane] = sv;
      Sp = sv;
    }
  }
  __syncthreads();
  // outputs, places distributed across 8 waves
  for (int u = w; u < U; u += 8) {
    int p = lastPG[v * TCAP + u];
    int li = lastIG[v * TCAP + u];
    int m = lastMG[v * TCAP + u];
    float acc = catb[li * 64 + lane];
    while (m) {
      int q = __ffs(m) - 1; m &= m - 1;
      acc += S_lds[q * 64 + lane];
    }
    atomicAdd(&out[(size_t)p * C + col], acc);
  }
}

// ---------------------------------------------------------------------------
extern "C" void kernel_launch(void* const* d_in, const int* in_sizes, int n_in,
                              void* d_out, int out_size, void* d_ws, size_t ws_size,
                              hipStream_t stream) {
  const float* emb      = (const float*)d_in[0];
  const float* Ws       = (const float*)d_in[1];
  const float* Wn       = (const float*)d_in[2];
  const float* bias     = (const float*)d_in[3];
  const int*   variants = (const int*)d_in[4];
  const int*   adj      = (const int*)d_in[5];
  const int*   ei       = (const int*)d_in[6];
  const int    E        = in_sizes[6] / 2;
  float* out            = (float*)d_out;

  char* base = (char*)d_ws;
  float* states = (float*)base;            base += (size_t)NSTATE * N * D * 4;
  float* Z      = (float*)base;            base += (size_t)N * 512 * 4;
  ushort* WtHi  = (ushort*)base;           base += (size_t)512 * 256 * 2;
  ushort* WtLo  = (ushort*)base;           base += (size_t)512 * 256 * 2;
  ushort* A0h   = (ushort*)base;           base += (size_t)N * D * 2;
  ushort* A0l   = (ushort*)base;           base += (size_t)N * D * 2;
  ushort* A1h   = (ushort*)base;           base += (size_t)N * D * 2;
  ushort* A1l   = (ushort*)base;           base += (size_t)N * D * 2;
  int* row_ptr  = (int*)base;              base += (N + 1) * 4;
  int* fillpos  = (int*)base;              base += N * 4;
  int* csr_src  = (int*)base;              base += (size_t)E * 4;
  int* stepP    = (int*)base;              base += V * L * FCAP * 4;
  int* stepDm   = (int*)base;              base += V * L * FCAP * 4;
  int* stepCnt  = (int*)base;              base += V * L * 4;
  int* hasG     = (int*)base;              base += V * L * 4;
  int* entP     = (int*)base;              base += V * TCAP * 4;
  int* entPrev  = (int*)base;              base += V * TCAP * 4;
  int* entDm    = (int*)base;              base += V * TCAP * 4;
  int* offsG    = (int*)base;              base += V * 17 * 4;
  int* kidxG    = (int*)base;              base += V * 16 * 4;
  int* tlG      = (int*)base;              base += V * 256 * 4;
  int* cmatG    = (int*)base;              base += V * 256 * 4;
  int* lastPG   = (int*)base;              base += V * TCAP * 4;
  int* lastIG   = (int*)base;              base += V * TCAP * 4;
  int* lastMG   = (int*)base;              base += V * TCAP * 4;
  int* cntG     = (int*)base;              base += V * 2 * 4;

  hipFuncSetAttribute((const void*)k_pi,
                      hipFuncAttributeMaxDynamicSharedMemorySize, PI_LDS_BYTES);

  k_init<<<512 + V * L, 256, 0, stream>>>(emb, Ws, Wn, states, WtHi, WtLo,
                                          A0h, A0l, out, adj, variants,
                                          stepP, stepDm, stepCnt, hasG, tlG);
  k_scan<<<1, 256, 0, stream>>>(ei, E, fillpos, row_ptr);
  k_fillB<<<128 + V, 256, 0, stream>>>(ei, E, fillpos, csr_src, stepP, stepDm,
                                       stepCnt, hasG, entP, entPrev, entDm,
                                       offsG, kidxG, cmatG, lastPG, lastIG,
                                       lastMG, cntG);

  ushort* AH[2] = {A0h, A1h};
  ushort* AL[2] = {A0l, A1l};
  for (int s = 0; s < NAPP; s++) {
    int cur = s & 1, nxt = cur ^ 1;
    k_gemm<<<dim3(64, 16), 256, 0, stream>>>(AH[cur], AL[cur], WtHi, WtLo, Z);
    k_comb<<<N / 4, 256, 0, stream>>>(Z, bias, row_ptr, csr_src,
                                      states + (size_t)(s + 1) * N * D,
                                      AH[nxt], AL[nxt]);
  }
  k_pi<<<V * 12, 512, PI_LDS_BYTES, stream>>>(states, out, variants, entP,
                                              entPrev, entDm, offsG, kidxG, tlG,
                                              cmatG, lastPG, lastIG, lastMG,
                                              cntG);
}

// Round 7
// 339.385 us; speedup vs baseline: 1.2274x; 1.0793x over previous
//
#include <hip/hip_runtime.h>

// Problem constants (fixed by the reference)
#define N 2048
#define D 256
#define C 768          // 3*D
#define V 2
#define L 16
#define NSTATE 15      // S_0..S_14 (step-15 mask provably empty)
#define NAPP 14        // encoder applications
#define TCAP 256       // canonical masked-entry cap per variant (expected ~107)
#define FCAP 64        // follower cap per step (expected ~32)

typedef __attribute__((ext_vector_type(8))) short bf16x8;
typedef __attribute__((ext_vector_type(4))) float f32x4;

__device__ __forceinline__ ushort bf16_rn(float x) {
  unsigned u = __float_as_uint(x);
  u += 0x7FFFu + ((u >> 16) & 1u);
  return (ushort)(u >> 16);
}
__device__ __forceinline__ float bf16_f(ushort h) {
  return __uint_as_float(((unsigned)h) << 16);
}

// Chunk-tiled operand layouts (chunk = 32 rows x 64 k = 2048 ushorts = 4 KB).
// (R4-validated, unswizzled)
__device__ __forceinline__ size_t a_addr(int row, int k) {
  return ((size_t)(row >> 5) * 4 + (k >> 6)) * 2048 + (row & 31) * 64 + (k & 63);
}
__device__ __forceinline__ size_t wt_addr(int n, int k) {
  return ((size_t)(n >> 5) * 4 + (k >> 6)) * 2048 + (n & 31) * 64 + (k & 63);
}

// ---------------------------------------------------------------------------
// k_init: blocks 0..511: states0 = emb; A0 bf16 split (chunked);
// Wt=[W_self|W_nbr]^T split (chunked); zero out.
// blocks 512..543: metaA (per (variant,step) follower lists + dest bitmasks).
// (validated R6)
// ---------------------------------------------------------------------------
__global__ __launch_bounds__(256) void k_init(
    const float* __restrict__ emb, const float* __restrict__ Ws,
    const float* __restrict__ Wn, float* __restrict__ states0,
    ushort* __restrict__ WtHi, ushort* __restrict__ WtLo,
    ushort* __restrict__ A0hi, ushort* __restrict__ A0lo,
    float* __restrict__ out,
    const int* __restrict__ adj, const int* __restrict__ variants,
    int* __restrict__ stepP, int* __restrict__ stepDm,
    int* __restrict__ stepCnt, int* __restrict__ hasG, int* __restrict__ tlG) {
  __shared__ int tl_sh[16];
  __shared__ int foll[FCAP], fbits[FCAP];
  __shared__ int sh_tc, sh_fcnt, sh_ecnt;
  int t = threadIdx.x;
  if (blockIdx.x < 512) {
    size_t i = (size_t)blockIdx.x * 256 + t;
    const size_t stride = (size_t)512 * 256;
    for (size_t x = i; x < (size_t)N * D; x += stride) {
      float v = emb[x];
      states0[x] = v;
      ushort h = bf16_rn(v);
      ushort l = bf16_rn(v - bf16_f(h));
      size_t a = a_addr((int)(x >> 8), (int)(x & 255));
      A0hi[a] = h;
      A0lo[a] = l;
    }
    for (size_t x = i; x < (size_t)512 * 256; x += stride) {
      int n = (int)(x >> 8), k = (int)(x & 255);
      float v = (n < 256) ? Ws[(size_t)k * 256 + n]
                          : Wn[(size_t)k * 256 + (n - 256)];
      ushort h = bf16_rn(v);
      size_t a = wt_addr(n, k);
      WtHi[a] = h;
      WtLo[a] = bf16_rn(v - bf16_f(h));
    }
    for (size_t x = i; x < (size_t)N * C; x += stride) out[x] = 0.f;
    return;
  }
  // ---- metaA ----
  int vi = blockIdx.x - 512;
  int v = vi / L, i = vi % L;
  int a = variants[vi];
  if (t == 0) {
    int cnt = 0;
    for (int j = i + 1; j < L; j++) {
      int x = variants[v * L + j];
      bool dup = false;
      for (int q = 0; q < cnt; q++) if (tl_sh[q] == x) dup = true;
      if (!dup) tl_sh[cnt++] = x;
    }
    sh_tc = cnt;
    sh_fcnt = 0;
    sh_ecnt = 0;
    for (int q = 0; q < cnt; q++) tlG[vi * 16 + q] = tl_sh[q];
  }
  __syncthreads();
  for (int p = t; p < N; p += 256) {
    if (adj[(size_t)a * N + p] != 0) {
      int f = atomicAdd(&sh_fcnt, 1);
      if (f < FCAP) foll[f] = p;
    }
  }
  __syncthreads();
  int fc = sh_fcnt < FCAP ? sh_fcnt : FCAP;
  int tc = sh_tc;
  for (int x = t; x < fc; x += 256) fbits[x] = 0;
  __syncthreads();
  for (int x = t; x < fc * tc; x += 256) {
    int fi = x / tc, q = x - fi * tc;
    if (adj[(size_t)foll[fi] * N + tl_sh[q]] != 0) atomicOr(&fbits[fi], 1 << q);
  }
  __syncthreads();
  for (int fi = t; fi < fc; fi += 256) {
    int bits = fbits[fi];
    if (bits) {
      int e = atomicAdd(&sh_ecnt, 1);
      stepP[vi * FCAP + e] = foll[fi];
      stepDm[vi * FCAP + e] = bits;
    }
  }
  __syncthreads();
  if (t == 0) {
    stepCnt[vi] = sh_ecnt;
    hasG[vi] = (sh_fcnt > 0);
  }
}

// ---------------------------------------------------------------------------
// k_scan v2: 1024-thread LDS histogram (int4-vectorized edge reads, 16 waves
// hiding HBM latency) + 256-thread exclusive scan -> row_ptr; fillpos =
// starts.  (R6's 256-thr scalar version was 50 us of exposed latency.)
// ---------------------------------------------------------------------------
__global__ __launch_bounds__(1024) void k_scan(const int* __restrict__ ei,
                                               int E, int* __restrict__ fillpos,
                                               int* __restrict__ row_ptr) {
  __shared__ int hist[N];            // 8 KB
  __shared__ int part[256];
  __shared__ int base[257];
  int t = threadIdx.x;
  for (int p = t; p < N; p += 1024) hist[p] = 0;
  __syncthreads();
  const int e4 = E >> 2;
  const int4* dsts = (const int4*)(ei + E);
  for (int g = t; g < e4; g += 1024) {
    int4 d = dsts[g];
    atomicAdd(&hist[d.x], 1);
    atomicAdd(&hist[d.y], 1);
    atomicAdd(&hist[d.z], 1);
    atomicAdd(&hist[d.w], 1);
  }
  for (int e = (e4 << 2) + t; e < E; e += 1024) atomicAdd(&hist[ei[E + e]], 1);
  __syncthreads();
  int v[8];
  int s = 0;
  if (t < 256) {
    for (int j = 0; j < 8; j++) { v[j] = hist[t * 8 + j]; s += v[j]; }
  }
  __syncthreads();
  if (t < 256) part[t] = s;
  __syncthreads();
  if (t == 0) {
    int acc = 0;
    for (int q = 0; q < 256; q++) { base[q] = acc; acc += part[q]; }
    base[256] = acc;
  }
  __syncthreads();
  if (t < 256) {
    int acc = base[t];
    for (int j = 0; j < 8; j++) {
      row_ptr[t * 8 + j] = acc;
      fillpos[t * 8 + j] = acc;
      acc += v[j];
    }
    if (t == 255) row_ptr[N] = base[256];
  }
}

// ---------------------------------------------------------------------------
// k_fillB: fused k_fill (blocks 0..127) + k_metaB (blocks 128..128+V-1).
// ---------------------------------------------------------------------------
__global__ __launch_bounds__(256) void k_fillB(
    const int* __restrict__ ei, int E, int* __restrict__ fillpos,
    int* __restrict__ csr_src,
    const int* __restrict__ stepP, const int* __restrict__ stepDm,
    const int* __restrict__ stepCnt, const int* __restrict__ hasG,
    int* __restrict__ entP, int* __restrict__ entPrev, int* __restrict__ entDm,
    int* __restrict__ offsG, int* __restrict__ kidxG, int* __restrict__ cmatG,
    int* __restrict__ lastPG, int* __restrict__ lastIG, int* __restrict__ lastMG,
    int* __restrict__ cntG) {
  __shared__ int pmask[N];           // 8 KB
  __shared__ int sP[16][FCAP];       // 4 KB
  __shared__ int sDm[16][FCAP];      // 4 KB
  __shared__ int cnt[16], offs[17];
  __shared__ int cmat_sh[256];       // 1 KB
  __shared__ int sh_u;
  int t = threadIdx.x;
  if (blockIdx.x < 128) {
    for (int e = blockIdx.x * 256 + t; e < E; e += 128 * 256) {
      int dst = ei[E + e];
      int pos = atomicAdd(&fillpos[dst], 1);
      csr_src[pos] = ei[e];
    }
    return;
  }
  int v = blockIdx.x - 128;
  for (int p = t; p < N; p += 256) pmask[p] = 0;
  for (int x = t; x < 256; x += 256) cmat_sh[x] = 0;
  if (t < 16) cnt[t] = stepCnt[v * L + t];
  if (t == 0) sh_u = 0;
  __syncthreads();
  if (t == 0) {
    int acc = 0;
    for (int i = 0; i < 16; i++) {
      offs[i] = acc < TCAP ? acc : TCAP;
      acc += cnt[i];
    }
    offs[16] = acc < TCAP ? acc : TCAP;
    cntG[v * 2 + 0] = offs[16];
    int k = 0;
    for (int i = 0; i < L; i++) {
      kidxG[v * 16 + i] = k;
      if (hasG[v * L + i]) k++;
    }
  }
  for (int x = t; x < 16 * FCAP; x += 256) {
    int i = x >> 6, f = x & 63;
    if (f < stepCnt[v * L + i]) {
      int p = stepP[(v * L + i) * FCAP + f];
      sP[i][f] = p;
      sDm[i][f] = stepDm[(v * L + i) * FCAP + f];
      atomicOr(&pmask[p], 1 << i);
    }
  }
  __syncthreads();
  for (int x = t; x < 16 * FCAP; x += 256) {
    int i = x >> 6, f = x & 63;
    if (f < cnt[i]) {
      int e = offs[i] + f;
      if (e < TCAP) {
        int p = sP[i][f];
        entP[v * TCAP + e] = p;
        entDm[v * TCAP + e] = sDm[i][f];
        int m = pmask[p] & ((1 << i) - 1);
        int prev = -1;
        if (m) {
          int j = 31 - __clz(m);
          int cj = cnt[j];
          for (int f2 = 0; f2 < cj; f2++)
            if (sP[j][f2] == p) { prev = offs[j] + f2; break; }
        }
        entPrev[v * TCAP + e] = prev;
      }
    }
  }
  __syncthreads();
  for (int p = t; p < N; p += 256) {
    int m = pmask[p];
    if (m) {
      int u = atomicAdd(&sh_u, 1);
      int j = 31 - __clz(m);
      int li = -1;
      int cj = cnt[j];
      for (int f2 = 0; f2 < cj; f2++)
        if (sP[j][f2] == p) { li = offs[j] + f2; break; }
      lastPG[v * TCAP + u] = p;
      lastIG[v * TCAP + u] = li;
      lastMG[v * TCAP + u] = m;
      int mm = m;
      while (mm) {
        int bi = __ffs(mm) - 1; mm &= mm - 1;
        int m2 = m & ((1 << bi) - 1);
        while (m2) {
          int bj = __ffs(m2) - 1; m2 &= m2 - 1;
          atomicAdd(&cmat_sh[bi * 16 + bj], 1);
        }
      }
    }
  }
  __syncthreads();
  if (t == 0) cntG[v * 2 + 1] = sh_u;
  for (int x = t; x < 256; x += 256) cmatG[v * 256 + x] = cmat_sh[x];
  for (int x = t; x < 17; x += 256) offsG[v * 17 + x] = offs[x];
}

// ---------------------------------------------------------------------------
// k_gemm: Z = A @ [W_self|W_nbr]  (M=2048, K=256, N=512), bf16 3-product
// split, fp32 accum.  LDS double-buffered; global prefetch of chunk c+1
// overlaps MFMA of chunk c.  (R4-validated; do not touch.)
// ---------------------------------------------------------------------------
__global__ __launch_bounds__(256) void k_gemm(
    const ushort* __restrict__ Ah, const ushort* __restrict__ Al,
    const ushort* __restrict__ Wh_g, const ushort* __restrict__ Wl_g,
    float* __restrict__ Z) {
  __shared__ __align__(16) ushort Ash[2][32][72], Asl[2][32][72];
  __shared__ __align__(16) ushort Wsh[2][32][72], Wsl[2][32][72];
  const int tid = threadIdx.x, wave = tid >> 6, lane = tid & 63;
  const int quad = lane >> 4, l16 = lane & 15;
  const int wr = wave >> 1, wc = wave & 1;
  const int mb = blockIdx.x, nb = blockIdx.y;
  const int sr = tid >> 3, sc = (tid & 7) * 8;

  f32x4 acc = {0.f, 0.f, 0.f, 0.f};
  size_t abase = (size_t)mb * 4 * 2048 + (size_t)tid * 8;
  size_t wbase = (size_t)nb * 4 * 2048 + (size_t)tid * 8;
  // stage chunk 0 into buf 0
  {
    uint4 ra  = *(const uint4*)&Ah[abase];
    uint4 rl  = *(const uint4*)&Al[abase];
    uint4 rwh = *(const uint4*)&Wh_g[wbase];
    uint4 rwl = *(const uint4*)&Wl_g[wbase];
    *(uint4*)&Ash[0][sr][sc] = ra;
    *(uint4*)&Asl[0][sr][sc] = rl;
    *(uint4*)&Wsh[0][sr][sc] = rwh;
    *(uint4*)&Wsl[0][sr][sc] = rwl;
  }
  __syncthreads();
#pragma unroll
  for (int c = 0; c < 4; c++) {
    const int rb = c & 1;
    uint4 ra, rl, rwh, rwl;
    if (c < 3) {
      size_t o = (size_t)(c + 1) * 2048;
      ra  = *(const uint4*)&Ah[abase + o];
      rl  = *(const uint4*)&Al[abase + o];
      rwh = *(const uint4*)&Wh_g[wbase + o];
      rwl = *(const uint4*)&Wl_g[wbase + o];
    }
#pragma unroll
    for (int kf = 0; kf < 2; kf++) {
      int ko = kf * 32 + quad * 8;
      bf16x8 a_h = *(const bf16x8*)&Ash[rb][wr * 16 + l16][ko];
      bf16x8 a_l = *(const bf16x8*)&Asl[rb][wr * 16 + l16][ko];
      bf16x8 w_h = *(const bf16x8*)&Wsh[rb][wc * 16 + l16][ko];
      bf16x8 w_l = *(const bf16x8*)&Wsl[rb][wc * 16 + l16][ko];
      acc = __builtin_amdgcn_mfma_f32_16x16x32_bf16(a_h, w_h, acc, 0, 0, 0);
      acc = __builtin_amdgcn_mfma_f32_16x16x32_bf16(a_h, w_l, acc, 0, 0, 0);
      acc = __builtin_amdgcn_mfma_f32_16x16x32_bf16(a_l, w_h, acc, 0, 0, 0);
    }
    if (c < 3) {
      const int wb = rb ^ 1;
      *(uint4*)&Ash[wb][sr][sc] = ra;
      *(uint4*)&Asl[wb][sr][sc] = rl;
      *(uint4*)&Wsh[wb][sr][sc] = rwh;
      *(uint4*)&Wsl[wb][sr][sc] = rwl;
      __syncthreads();
    }
  }
  int col = nb * 32 + wc * 16 + l16;
  int row0 = mb * 32 + wr * 16 + quad * 4;
#pragma unroll
  for (int r = 0; r < 4; r++)
    Z[(size_t)(row0 + r) * 512 + col] = acc[r];
}

// ---------------------------------------------------------------------------
// k_comb: next[r] = relu(Z1[r] + sum_{e in in(r)} Z2[src_e] + b).
// One wave per row; 4-way unrolled gather.  (R4-validated)
// ---------------------------------------------------------------------------
__global__ __launch_bounds__(256) void k_comb(
    const float* __restrict__ Z, const float* __restrict__ bias,
    const int* __restrict__ row_ptr, const int* __restrict__ csr_src,
    float* __restrict__ stnext, ushort* __restrict__ NAh,
    ushort* __restrict__ NAl) {
  int row = blockIdx.x * 4 + (threadIdx.x >> 6);
  int lane = threadIdx.x & 63;
  const float4* Zp = (const float4*)Z;
  float4 acc = Zp[(size_t)row * 128 + lane];            // Z1 self
  float4 acc2 = {0.f, 0.f, 0.f, 0.f};
  float4 acc3 = {0.f, 0.f, 0.f, 0.f};
  float4 acc4 = {0.f, 0.f, 0.f, 0.f};
  int e0 = row_ptr[row], e1 = row_ptr[row + 1];
  int e = e0;
  for (; e + 3 < e1; e += 4) {
    int s0 = csr_src[e], s1 = csr_src[e + 1];
    int s2 = csr_src[e + 2], s3 = csr_src[e + 3];
    float4 x0 = Zp[(size_t)s0 * 128 + 64 + lane];
    float4 x1 = Zp[(size_t)s1 * 128 + 64 + lane];
    float4 x2 = Zp[(size_t)s2 * 128 + 64 + lane];
    float4 x3 = Zp[(size_t)s3 * 128 + 64 + lane];
    acc.x += x0.x; acc.y += x0.y; acc.z += x0.z; acc.w += x0.w;
    acc2.x += x1.x; acc2.y += x1.y; acc2.z += x1.z; acc2.w += x1.w;
    acc3.x += x2.x; acc3.y += x2.y; acc3.z += x2.z; acc3.w += x2.w;
    acc4.x += x3.x; acc4.y += x3.y; acc4.z += x3.z; acc4.w += x3.w;
  }
  for (; e < e1; e++) {
    float4 x0 = Zp[(size_t)csr_src[e] * 128 + 64 + lane];
    acc.x += x0.x; acc.y += x0.y; acc.z += x0.z; acc.w += x0.w;
  }
  float4 bv = ((const float4*)bias)[lane];
  float v0 = fmaxf(acc.x + acc2.x + acc3.x + acc4.x + bv.x, 0.f);
  float v1 = fmaxf(acc.y + acc2.y + acc3.y + acc4.y + bv.y, 0.f);
  float v2 = fmaxf(acc.z + acc2.z + acc3.z + acc4.z + bv.z, 0.f);
  float v3 = fmaxf(acc.w + acc2.w + acc3.w + acc4.w + bv.w, 0.f);
  *(float4*)(stnext + (size_t)row * D + lane * 4) = make_float4(v0, v1, v2, v3);
  ushort h0 = bf16_rn(v0), h1 = bf16_rn(v1), h2 = bf16_rn(v2), h3 = bf16_rn(v3);
  size_t ca = a_addr(row, lane * 4);
  *(ushort4*)&NAh[ca] = make_ushort4(h0, h1, h2, h3);
  *(ushort4*)&NAl[ca] = make_ushort4(
      bf16_rn(v0 - bf16_f(h0)), bf16_rn(v1 - bf16_f(h1)),
      bf16_rn(v2 - bf16_f(h2)), bf16_rn(v3 - bf16_f(h3)));
}

// ---------------------------------------------------------------------------
// k_pi: LINEAR reformulation, 512 threads/block (8 waves).  (validated R6)
// ---------------------------------------------------------------------------
#define PI_LDS_BYTES (TCAP * 64 * 4 + 16 * 64 * 4 + 16 * 64 * 4 + 256 * 4 + \
                      3 * TCAP * 4 + 17 * 4 + 16 * 4 + 256 * 4)
__global__ __launch_bounds__(512) void k_pi(
    const float* __restrict__ states, float* __restrict__ out,
    const int* __restrict__ variants,
    const int* __restrict__ entP, const int* __restrict__ entPrev,
    const int* __restrict__ entDm, const int* __restrict__ offsG,
    const int* __restrict__ kidxG, const int* __restrict__ tlG,
    const int* __restrict__ cmatG, const int* __restrict__ lastPG,
    const int* __restrict__ lastIG, const int* __restrict__ lastMG,
    const int* __restrict__ cntG) {
  extern __shared__ __align__(16) float smf[];
  float* catb = smf;                       // [TCAP][64]  (becomes pref)
  float* S_lds = catb + TCAP * 64;         // [16][64]
  float* aS = S_lds + 16 * 64;             // [16][64] per-step sums
  float* cmatf = aS + 16 * 64;             // [256]
  int* eP  = (int*)(cmatf + 256);          // [TCAP]
  int* ePr = eP + TCAP;
  int* eDm = ePr + TCAP;
  int* offs = eDm + TCAP;                  // [17]
  int* kidx = offs + 17;                   // [16]
  int* tl = kidx + 16;                     // [256]
  int v = blockIdx.x / 12, cgi = blockIdx.x % 12;
  int grp = cgi >> 2;
  int tid = threadIdx.x, lane = tid & 63, w = tid >> 6;   // w in 0..7
  int cl = (cgi & 3) * 64 + lane;          // 0..255 within third
  int col = cgi * 64 + lane;               // 0..767

  int T = cntG[v * 2 + 0], U = cntG[v * 2 + 1];
  for (int x = tid; x < T; x += 512) {
    eP[x] = entP[v * TCAP + x];
    ePr[x] = entPrev[v * TCAP + x];
    eDm[x] = entDm[v * TCAP + x];
  }
  for (int x = tid; x < 17; x += 512) offs[x] = offsG[v * 17 + x];
  if (tid < 16) kidx[tid] = kidxG[v * 16 + tid];
  for (int x = tid; x < 256; x += 512) {
    tl[x] = tlG[v * 256 + x];
    cmatf[x] = (float)cmatG[v * 256 + x];
  }
  __syncthreads();

  // cat fill: 8 waves split the entries of each step
  for (int i = 0; i < L; i++) {
    int kk = kidx[i]; if (kk > NSTATE - 1) kk = NSTATE - 1;
    const float* embS = states + (size_t)kk * N * D;
    int o0 = offs[i], o1 = offs[i + 1];
    if (grp == 0) {
      for (int e = o0 + w; e < o1; e += 8)
        catb[e * 64 + lane] = embS[(size_t)eP[e] * D + cl];
    } else if (grp == 1) {
      float embA = embS[(size_t)variants[v * L + i] * D + cl];
      for (int e = o0 + w; e < o1; e += 8) catb[e * 64 + lane] = embA;
    } else {
      for (int e = o0 + w; e < o1; e += 8) {
        float sa = 0.f;
        int bm = eDm[e];
        while (bm) {
          int q = __ffs(bm) - 1; bm &= bm - 1;
          sa += embS[(size_t)tl[i * 16 + q] * D + cl];
        }
        catb[e * 64 + lane] = sa;
      }
    }
  }
  __syncthreads();
  // prefix over place-chains, chains distributed across 8 waves
  for (int u = w; u < U; u += 8) {
    int li = lastIG[v * TCAP + u];
    int len = 0;
    for (int c2 = li; c2 >= 0; c2 = ePr[c2]) len++;
    for (int j = 1; j < len; j++) {        // root -> last order
      int c2 = li;
      for (int k = 0; k < len - 1 - j; k++) c2 = ePr[c2];
      catb[c2 * 64 + lane] += catb[ePr[c2] * 64 + lane];
    }
  }
  __syncthreads();
  // per-step sums of pref
  for (int i = w; i < 16; i += 8) {
    float a = 0.f;
    for (int e = offs[i]; e < offs[i + 1]; e++) a += catb[e * 64 + lane];
    aS[i * 64 + lane] = a;
  }
  __syncthreads();
  // S recurrence (serial over 16 steps, wave 0)
  if (w == 0) {
    float S[16];
    float Sp = 0.f;
#pragma unroll
    for (int i = 0; i < 16; i++) {
      float sv = Sp + aS[i * 64 + lane];
#pragma unroll
      for (int j = 0; j < 16; j++)
        if (j < i) sv += cmatf[i * 16 + j] * S[j];
      S[i] = sv;
      S_lds[i * 64 + lane] = sv;
      Sp = sv;
    }
  }
  __syncthreads();
  // outputs, places distributed across 8 waves
  for (int u = w; u < U; u += 8) {
    int p = lastPG[v * TCAP + u];
    int li = lastIG[v * TCAP + u];
    int m = lastMG[v * TCAP + u];
    float acc = catb[li * 64 + lane];
    while (m) {
      int q = __ffs(m) - 1; m &= m - 1;
      acc += S_lds[q * 64 + lane];
    }
    atomicAdd(&out[(size_t)p * C + col], acc);
  }
}

// ---------------------------------------------------------------------------
extern "C" void kernel_launch(void* const* d_in, const int* in_sizes, int n_in,
                              void* d_out, int out_size, void* d_ws, size_t ws_size,
                              hipStream_t stream) {
  const float* emb      = (const float*)d_in[0];
  const float* Ws       = (const float*)d_in[1];
  const float* Wn       = (const float*)d_in[2];
  const float* bias     = (const float*)d_in[3];
  const int*   variants = (const int*)d_in[4];
  const int*   adj      = (const int*)d_in[5];
  const int*   ei       = (const int*)d_in[6];
  const int    E        = in_sizes[6] / 2;
  float* out            = (float*)d_out;

  char* base = (char*)d_ws;
  float* states = (float*)base;            base += (size_t)NSTATE * N * D * 4;
  float* Z      = (float*)base;            base += (size_t)N * 512 * 4;
  ushort* WtHi  = (ushort*)base;           base += (size_t)512 * 256 * 2;
  ushort* WtLo  = (ushort*)base;           base += (size_t)512 * 256 * 2;
  ushort* A0h   = (ushort*)base;           base += (size_t)N * D * 2;
  ushort* A0l   = (ushort*)base;           base += (size_t)N * D * 2;
  ushort* A1h   = (ushort*)base;           base += (size_t)N * D * 2;
  ushort* A1l   = (ushort*)base;           base += (size_t)N * D * 2;
  int* row_ptr  = (int*)base;              base += (N + 1) * 4;
  int* fillpos  = (int*)base;              base += N * 4;
  int* csr_src  = (int*)base;              base += (size_t)E * 4;
  int* stepP    = (int*)base;              base += V * L * FCAP * 4;
  int* stepDm   = (int*)base;              base += V * L * FCAP * 4;
  int* stepCnt  = (int*)base;              base += V * L * 4;
  int* hasG     = (int*)base;              base += V * L * 4;
  int* entP     = (int*)base;              base += V * TCAP * 4;
  int* entPrev  = (int*)base;              base += V * TCAP * 4;
  int* entDm    = (int*)base;              base += V * TCAP * 4;
  int* offsG    = (int*)base;              base += V * 17 * 4;
  int* kidxG    = (int*)base;              base += V * 16 * 4;
  int* tlG      = (int*)base;              base += V * 256 * 4;
  int* cmatG    = (int*)base;              base += V * 256 * 4;
  int* lastPG   = (int*)base;              base += V * TCAP * 4;
  int* lastIG   = (int*)base;              base += V * TCAP * 4;
  int* lastMG   = (int*)base;              base += V * TCAP * 4;
  int* cntG     = (int*)base;              base += V * 2 * 4;

  hipFuncSetAttribute((const void*)k_pi,
                      hipFuncAttributeMaxDynamicSharedMemorySize, PI_LDS_BYTES);

  k_init<<<512 + V * L, 256, 0, stream>>>(emb, Ws, Wn, states, WtHi, WtLo,
                                          A0h, A0l, out, adj, variants,
                                          stepP, stepDm, stepCnt, hasG, tlG);
  k_scan<<<1, 1024, 0, stream>>>(ei, E, fillpos, row_ptr);
  k_fillB<<<128 + V, 256, 0, stream>>>(ei, E, fillpos, csr_src, stepP, stepDm,
                                       stepCnt, hasG, entP, entPrev, entDm,
                                       offsG, kidxG, cmatG, lastPG, lastIG,
                                       lastMG, cntG);

  ushort* AH[2] = {A0h, A1h};
  ushort* AL[2] = {A0l, A1l};
  for (int s = 0; s < NAPP; s++) {
    int cur = s & 1, nxt = cur ^ 1;
    k_gemm<<<dim3(64, 16), 256, 0, stream>>>(AH[cur], AL[cur], WtHi, WtLo, Z);
    k_comb<<<N / 4, 256, 0, stream>>>(Z, bias, row_ptr, csr_src,
                                      states + (size_t)(s + 1) * N * D,
                                      AH[nxt], AL[nxt]);
  }
  k_pi<<<V * 12, 512, PI_LDS_BYTES, stream>>>(states, out, variants, entP,
                                              entPrev, entDm, offsG, kidxG, tlG,
                                              cmatG, lastPG, lastIG, lastMG,
                                              cntG);
}

// Round 8
// 334.465 us; speedup vs baseline: 1.2455x; 1.0147x over previous
//
#include <hip/hip_runtime.h>

// Problem constants (fixed by the reference)
#define N 2048
#define D 256
#define C 768          // 3*D
#define V 2
#define L 16
#define NSTATE 15      // S_0..S_14 (step-15 mask provably empty)
#define NAPP 14        // encoder applications
#define TCAP 256       // canonical masked-entry cap per variant (expected ~107)
#define FCAP 64        // follower cap per step (expected ~32)

typedef __attribute__((ext_vector_type(8))) short bf16x8;
typedef __attribute__((ext_vector_type(4))) float f32x4;

__device__ __forceinline__ ushort bf16_rn(float x) {
  unsigned u = __float_as_uint(x);
  u += 0x7FFFu + ((u >> 16) & 1u);
  return (ushort)(u >> 16);
}
__device__ __forceinline__ float bf16_f(ushort h) {
  return __uint_as_float(((unsigned)h) << 16);
}

// Chunk-tiled operand layouts (chunk = 32 rows x 64 k = 2048 ushorts = 4 KB).
__device__ __forceinline__ size_t a_addr(int row, int k) {
  return ((size_t)(row >> 5) * 4 + (k >> 6)) * 2048 + (row & 31) * 64 + (k & 63);
}
__device__ __forceinline__ size_t wt_addr(int n, int k) {
  return ((size_t)(n >> 5) * 4 + (k >> 6)) * 2048 + (n & 31) * 64 + (k & 63);
}

// ---------------------------------------------------------------------------
// k_init: blocks 0..511: states0 = emb; A0 bf16 split; Wt split; zero out.
// blocks 512..543: metaA.  block 544: edge histogram + exclusive scan ->
// row_ptr/fillpos (independent of other blocks; int4-vectorized loads).
// ---------------------------------------------------------------------------
__global__ __launch_bounds__(256) void k_init(
    const float* __restrict__ emb, const float* __restrict__ Ws,
    const float* __restrict__ Wn, float* __restrict__ states0,
    ushort* __restrict__ WtHi, ushort* __restrict__ WtLo,
    ushort* __restrict__ A0hi, ushort* __restrict__ A0lo,
    float* __restrict__ out,
    const int* __restrict__ adj, const int* __restrict__ variants,
    int* __restrict__ stepP, int* __restrict__ stepDm,
    int* __restrict__ stepCnt, int* __restrict__ hasG, int* __restrict__ tlG,
    const int* __restrict__ ei, int E, int* __restrict__ fillpos,
    int* __restrict__ row_ptr) {
  __shared__ int tl_sh[16];
  __shared__ int foll[FCAP], fbits[FCAP];
  __shared__ int sh_tc, sh_fcnt, sh_ecnt;
  __shared__ int hist[N];            // 8 KB (scan block only)
  __shared__ int part[256];
  __shared__ int base[257];
  int t = threadIdx.x;
  if (blockIdx.x < 512) {
    size_t i = (size_t)blockIdx.x * 256 + t;
    const size_t stride = (size_t)512 * 256;
    for (size_t x = i; x < (size_t)N * D; x += stride) {
      float v = emb[x];
      states0[x] = v;
      ushort h = bf16_rn(v);
      ushort l = bf16_rn(v - bf16_f(h));
      size_t a = a_addr((int)(x >> 8), (int)(x & 255));
      A0hi[a] = h;
      A0lo[a] = l;
    }
    for (size_t x = i; x < (size_t)512 * 256; x += stride) {
      int n = (int)(x >> 8), k = (int)(x & 255);
      float v = (n < 256) ? Ws[(size_t)k * 256 + n]
                          : Wn[(size_t)k * 256 + (n - 256)];
      ushort h = bf16_rn(v);
      size_t a = wt_addr(n, k);
      WtHi[a] = h;
      WtLo[a] = bf16_rn(v - bf16_f(h));
    }
    for (size_t x = i; x < (size_t)N * C; x += stride) out[x] = 0.f;
    return;
  }
  if (blockIdx.x < 544) {
    // ---- metaA ----
    int vi = blockIdx.x - 512;
    int v = vi / L, i = vi % L;
    int a = variants[vi];
    if (t == 0) {
      int cnt = 0;
      for (int j = i + 1; j < L; j++) {
        int x = variants[v * L + j];
        bool dup = false;
        for (int q = 0; q < cnt; q++) if (tl_sh[q] == x) dup = true;
        if (!dup) tl_sh[cnt++] = x;
      }
      sh_tc = cnt;
      sh_fcnt = 0;
      sh_ecnt = 0;
      for (int q = 0; q < cnt; q++) tlG[vi * 16 + q] = tl_sh[q];
    }
    __syncthreads();
    for (int p = t; p < N; p += 256) {
      if (adj[(size_t)a * N + p] != 0) {
        int f = atomicAdd(&sh_fcnt, 1);
        if (f < FCAP) foll[f] = p;
      }
    }
    __syncthreads();
    int fc = sh_fcnt < FCAP ? sh_fcnt : FCAP;
    int tc = sh_tc;
    for (int x = t; x < fc; x += 256) fbits[x] = 0;
    __syncthreads();
    for (int x = t; x < fc * tc; x += 256) {
      int fi = x / tc, q = x - fi * tc;
      if (adj[(size_t)foll[fi] * N + tl_sh[q]] != 0) atomicOr(&fbits[fi], 1 << q);
    }
    __syncthreads();
    for (int fi = t; fi < fc; fi += 256) {
      int bits = fbits[fi];
      if (bits) {
        int e = atomicAdd(&sh_ecnt, 1);
        stepP[vi * FCAP + e] = foll[fi];
        stepDm[vi * FCAP + e] = bits;
      }
    }
    __syncthreads();
    if (t == 0) {
      stepCnt[vi] = sh_ecnt;
      hasG[vi] = (sh_fcnt > 0);
    }
    return;
  }
  // ---- scan block (no dependency on other blocks of this kernel) ----
  for (int p = t; p < N; p += 256) hist[p] = 0;
  __syncthreads();
  {
    const int e4 = E >> 2;
    const int4* dsts = (const int4*)(ei + E);
    for (int g = t; g < e4; g += 256) {
      int4 d = dsts[g];
      atomicAdd(&hist[d.x], 1);
      atomicAdd(&hist[d.y], 1);
      atomicAdd(&hist[d.z], 1);
      atomicAdd(&hist[d.w], 1);
    }
    for (int e = (e4 << 2) + t; e < E; e += 256) atomicAdd(&hist[ei[E + e]], 1);
  }
  __syncthreads();
  int vv[8];
  int s = 0;
  for (int j = 0; j < 8; j++) { vv[j] = hist[t * 8 + j]; s += vv[j]; }
  part[t] = s;
  __syncthreads();
  if (t == 0) {
    int acc = 0;
    for (int q = 0; q < 256; q++) { base[q] = acc; acc += part[q]; }
    base[256] = acc;
  }
  __syncthreads();
  int acc = base[t];
  for (int j = 0; j < 8; j++) {
    row_ptr[t * 8 + j] = acc;
    fillpos[t * 8 + j] = acc;
    acc += vv[j];
  }
  if (t == 255) row_ptr[N] = base[256];
}

// ---------------------------------------------------------------------------
// gemm_body: Z = A @ [W_self|W_nbr] (M=2048,K=256,N=512), bf16 3-product
// split, fp32 accum, LDS double-buffered.  (R4-validated schedule, verbatim;
// LDS carved from a raw 36.9 KB buffer so k_gemm0 can reuse it.)
// ---------------------------------------------------------------------------
__device__ __forceinline__ void gemm_body(
    const ushort* __restrict__ Ah, const ushort* __restrict__ Al,
    const ushort* __restrict__ Wh_g, const ushort* __restrict__ Wl_g,
    float* __restrict__ Z, ushort* smem, const int mb, const int nb,
    const int tid) {
  ushort (*Ash)[32][72] = (ushort (*)[32][72])(smem);
  ushort (*Asl)[32][72] = (ushort (*)[32][72])(smem + 4608);
  ushort (*Wsh)[32][72] = (ushort (*)[32][72])(smem + 9216);
  ushort (*Wsl)[32][72] = (ushort (*)[32][72])(smem + 13824);
  const int wave = tid >> 6, lane = tid & 63;
  const int quad = lane >> 4, l16 = lane & 15;
  const int wr = wave >> 1, wc = wave & 1;
  const int sr = tid >> 3, sc = (tid & 7) * 8;

  f32x4 acc = {0.f, 0.f, 0.f, 0.f};
  size_t abase = (size_t)mb * 4 * 2048 + (size_t)tid * 8;
  size_t wbase = (size_t)nb * 4 * 2048 + (size_t)tid * 8;
  {
    uint4 ra  = *(const uint4*)&Ah[abase];
    uint4 rl  = *(const uint4*)&Al[abase];
    uint4 rwh = *(const uint4*)&Wh_g[wbase];
    uint4 rwl = *(const uint4*)&Wl_g[wbase];
    *(uint4*)&Ash[0][sr][sc] = ra;
    *(uint4*)&Asl[0][sr][sc] = rl;
    *(uint4*)&Wsh[0][sr][sc] = rwh;
    *(uint4*)&Wsl[0][sr][sc] = rwl;
  }
  __syncthreads();
#pragma unroll
  for (int c = 0; c < 4; c++) {
    const int rb = c & 1;
    uint4 ra, rl, rwh, rwl;
    if (c < 3) {
      size_t o = (size_t)(c + 1) * 2048;
      ra  = *(const uint4*)&Ah[abase + o];
      rl  = *(const uint4*)&Al[abase + o];
      rwh = *(const uint4*)&Wh_g[wbase + o];
      rwl = *(const uint4*)&Wl_g[wbase + o];
    }
#pragma unroll
    for (int kf = 0; kf < 2; kf++) {
      int ko = kf * 32 + quad * 8;
      bf16x8 a_h = *(const bf16x8*)&Ash[rb][wr * 16 + l16][ko];
      bf16x8 a_l = *(const bf16x8*)&Asl[rb][wr * 16 + l16][ko];
      bf16x8 w_h = *(const bf16x8*)&Wsh[rb][wc * 16 + l16][ko];
      bf16x8 w_l = *(const bf16x8*)&Wsl[rb][wc * 16 + l16][ko];
      acc = __builtin_amdgcn_mfma_f32_16x16x32_bf16(a_h, w_h, acc, 0, 0, 0);
      acc = __builtin_amdgcn_mfma_f32_16x16x32_bf16(a_h, w_l, acc, 0, 0, 0);
      acc = __builtin_amdgcn_mfma_f32_16x16x32_bf16(a_l, w_h, acc, 0, 0, 0);
    }
    if (c < 3) {
      const int wb = rb ^ 1;
      *(uint4*)&Ash[wb][sr][sc] = ra;
      *(uint4*)&Asl[wb][sr][sc] = rl;
      *(uint4*)&Wsh[wb][sr][sc] = rwh;
      *(uint4*)&Wsl[wb][sr][sc] = rwl;
      __syncthreads();
    }
  }
  int col = nb * 32 + wc * 16 + l16;
  int row0 = mb * 32 + wr * 16 + quad * 4;
#pragma unroll
  for (int r = 0; r < 4; r++)
    Z[(size_t)(row0 + r) * 512 + col] = acc[r];
}

// ---------------------------------------------------------------------------
// k_gemm: plain GEMM iteration (s = 1..13).
// ---------------------------------------------------------------------------
__global__ __launch_bounds__(256) void k_gemm(
    const ushort* __restrict__ Ah, const ushort* __restrict__ Al,
    const ushort* __restrict__ Wh_g, const ushort* __restrict__ Wl_g,
    float* __restrict__ Z) {
  __shared__ __align__(16) ushort smem[18432];   // 36.9 KB
  gemm_body(Ah, Al, Wh_g, Wl_g, Z, smem, blockIdx.x, blockIdx.y, threadIdx.x);
}

// ---------------------------------------------------------------------------
// k_gemm0: s=0 GEMM (nb<16) fused with csr scatter-fill (aux 0..127) and
// metaB (aux 128..128+V-1).  Aux LDS carved from the same buffer.
// ---------------------------------------------------------------------------
__global__ __launch_bounds__(256) void k_gemm0(
    const ushort* __restrict__ Ah, const ushort* __restrict__ Al,
    const ushort* __restrict__ Wh_g, const ushort* __restrict__ Wl_g,
    float* __restrict__ Z,
    const int* __restrict__ ei, int E, int* __restrict__ fillpos,
    int* __restrict__ csr_src,
    const int* __restrict__ stepP, const int* __restrict__ stepDm,
    const int* __restrict__ stepCnt, const int* __restrict__ hasG,
    int* __restrict__ entP, int* __restrict__ entPrev, int* __restrict__ entDm,
    int* __restrict__ offsG, int* __restrict__ kidxG, int* __restrict__ cmatG,
    int* __restrict__ lastPG, int* __restrict__ lastIG, int* __restrict__ lastMG,
    int* __restrict__ cntG) {
  __shared__ __align__(16) ushort smem[18432];   // 36.9 KB
  int t = threadIdx.x;
  if (blockIdx.y < 16) {
    gemm_body(Ah, Al, Wh_g, Wl_g, Z, smem, blockIdx.x, blockIdx.y, t);
    return;
  }
  int aux = (blockIdx.y - 16) * 64 + blockIdx.x;   // 0..191
  if (aux < 128) {
    for (int e = aux * 256 + t; e < E; e += 128 * 256) {
      int dst = ei[E + e];
      int pos = atomicAdd(&fillpos[dst], 1);
      csr_src[pos] = ei[e];
    }
    return;
  }
  if (aux >= 128 + V) return;
  int vb = aux - 128;
  // metaB LDS carve (17.5 KB of the 36.9 KB buffer)
  int* pmask = (int*)smem;                         // [N]
  int (*sP)[FCAP] = (int (*)[FCAP])(pmask + N);    // [16][FCAP]
  int (*sDm)[FCAP] = (int (*)[FCAP])((int*)sP + 16 * FCAP);
  int* cnt = (int*)sDm + 16 * FCAP;                // [16]
  int* offs = cnt + 16;                            // [17]
  int* cmat_sh = offs + 17;                        // [256]
  int* sh_u = cmat_sh + 256;                       // [1]
  for (int p = t; p < N; p += 256) pmask[p] = 0;
  for (int x = t; x < 256; x += 256) cmat_sh[x] = 0;
  if (t < 16) cnt[t] = stepCnt[vb * L + t];
  if (t == 0) *sh_u = 0;
  __syncthreads();
  if (t == 0) {
    int acc = 0;
    for (int i = 0; i < 16; i++) {
      offs[i] = acc < TCAP ? acc : TCAP;
      acc += cnt[i];
    }
    offs[16] = acc < TCAP ? acc : TCAP;
    cntG[vb * 2 + 0] = offs[16];
    int k = 0;
    for (int i = 0; i < L; i++) {
      kidxG[vb * 16 + i] = k;
      if (hasG[vb * L + i]) k++;
    }
  }
  for (int x = t; x < 16 * FCAP; x += 256) {
    int i = x >> 6, f = x & 63;
    if (f < stepCnt[vb * L + i]) {
      int p = stepP[(vb * L + i) * FCAP + f];
      sP[i][f] = p;
      sDm[i][f] = stepDm[(vb * L + i) * FCAP + f];
      atomicOr(&pmask[p], 1 << i);
    }
  }
  __syncthreads();
  for (int x = t; x < 16 * FCAP; x += 256) {
    int i = x >> 6, f = x & 63;
    if (f < cnt[i]) {
      int e = offs[i] + f;
      if (e < TCAP) {
        int p = sP[i][f];
        entP[vb * TCAP + e] = p;
        entDm[vb * TCAP + e] = sDm[i][f];
        int m = pmask[p] & ((1 << i) - 1);
        int prev = -1;
        if (m) {
          int j = 31 - __clz(m);
          int cj = cnt[j];
          for (int f2 = 0; f2 < cj; f2++)
            if (sP[j][f2] == p) { prev = offs[j] + f2; break; }
        }
        entPrev[vb * TCAP + e] = prev;
      }
    }
  }
  __syncthreads();
  for (int p = t; p < N; p += 256) {
    int m = pmask[p];
    if (m) {
      int u = atomicAdd(sh_u, 1);
      int j = 31 - __clz(m);
      int li = -1;
      int cj = cnt[j];
      for (int f2 = 0; f2 < cj; f2++)
        if (sP[j][f2] == p) { li = offs[j] + f2; break; }
      lastPG[vb * TCAP + u] = p;
      lastIG[vb * TCAP + u] = li;
      lastMG[vb * TCAP + u] = m;
      int mm = m;
      while (mm) {
        int bi = __ffs(mm) - 1; mm &= mm - 1;
        int m2 = m & ((1 << bi) - 1);
        while (m2) {
          int bj = __ffs(m2) - 1; m2 &= m2 - 1;
          atomicAdd(&cmat_sh[bi * 16 + bj], 1);
        }
      }
    }
  }
  __syncthreads();
  if (t == 0) cntG[vb * 2 + 1] = *sh_u;
  for (int x = t; x < 256; x += 256) cmatG[vb * 256 + x] = cmat_sh[x];
  for (int x = t; x < 17; x += 256) offsG[vb * 17 + x] = offs[x];
}

// ---------------------------------------------------------------------------
// k_comb: next[r] = relu(Z1[r] + sum_{e in in(r)} Z2[src_e] + b).
// One wave per row; 8-deep gather (8 accumulators, 8 x 1 KB loads in flight),
// 4-wide + scalar tail.
// ---------------------------------------------------------------------------
__global__ __launch_bounds__(256) void k_comb(
    const float* __restrict__ Z, const float* __restrict__ bias,
    const int* __restrict__ row_ptr, const int* __restrict__ csr_src,
    float* __restrict__ stnext, ushort* __restrict__ NAh,
    ushort* __restrict__ NAl) {
  int row = blockIdx.x * 4 + (threadIdx.x >> 6);
  int lane = threadIdx.x & 63;
  const float4* Zp = (const float4*)Z;
  float4 self = Zp[(size_t)row * 128 + lane];            // Z1 self
  float4 b0 = {0.f, 0.f, 0.f, 0.f}, b1 = b0, b2 = b0, b3 = b0;
  float4 b4 = b0, b5 = b0, b6 = b0, b7 = b0;
  int e0 = row_ptr[row], e1 = row_ptr[row + 1];
  int e = e0;
  for (; e + 7 < e1; e += 8) {
    int s0 = csr_src[e],     s1 = csr_src[e + 1];
    int s2 = csr_src[e + 2], s3 = csr_src[e + 3];
    int s4 = csr_src[e + 4], s5 = csr_src[e + 5];
    int s6 = csr_src[e + 6], s7 = csr_src[e + 7];
    float4 x0 = Zp[(size_t)s0 * 128 + 64 + lane];
    float4 x1 = Zp[(size_t)s1 * 128 + 64 + lane];
    float4 x2 = Zp[(size_t)s2 * 128 + 64 + lane];
    float4 x3 = Zp[(size_t)s3 * 128 + 64 + lane];
    float4 x4 = Zp[(size_t)s4 * 128 + 64 + lane];
    float4 x5 = Zp[(size_t)s5 * 128 + 64 + lane];
    float4 x6 = Zp[(size_t)s6 * 128 + 64 + lane];
    float4 x7 = Zp[(size_t)s7 * 128 + 64 + lane];
    b0.x += x0.x; b0.y += x0.y; b0.z += x0.z; b0.w += x0.w;
    b1.x += x1.x; b1.y += x1.y; b1.z += x1.z; b1.w += x1.w;
    b2.x += x2.x; b2.y += x2.y; b2.z += x2.z; b2.w += x2.w;
    b3.x += x3.x; b3.y += x3.y; b3.z += x3.z; b3.w += x3.w;
    b4.x += x4.x; b4.y += x4.y; b4.z += x4.z; b4.w += x4.w;
    b5.x += x5.x; b5.y += x5.y; b5.z += x5.z; b5.w += x5.w;
    b6.x += x6.x; b6.y += x6.y; b6.z += x6.z; b6.w += x6.w;
    b7.x += x7.x; b7.y += x7.y; b7.z += x7.z; b7.w += x7.w;
  }
  if (e + 3 < e1) {
    int s0 = csr_src[e],     s1 = csr_src[e + 1];
    int s2 = csr_src[e + 2], s3 = csr_src[e + 3];
    float4 x0 = Zp[(size_t)s0 * 128 + 64 + lane];
    float4 x1 = Zp[(size_t)s1 * 128 + 64 + lane];
    float4 x2 = Zp[(size_t)s2 * 128 + 64 + lane];
    float4 x3 = Zp[(size_t)s3 * 128 + 64 + lane];
    b0.x += x0.x; b0.y += x0.y; b0.z += x0.z; b0.w += x0.w;
    b1.x += x1.x; b1.y += x1.y; b1.z += x1.z; b1.w += x1.w;
    b2.x += x2.x; b2.y += x2.y; b2.z += x2.z; b2.w += x2.w;
    b3.x += x3.x; b3.y += x3.y; b3.z += x3.z; b3.w += x3.w;
    e += 4;
  }
  for (; e < e1; e++) {
    float4 x0 = Zp[(size_t)csr_src[e] * 128 + 64 + lane];
    b0.x += x0.x; b0.y += x0.y; b0.z += x0.z; b0.w += x0.w;
  }
  float4 bv = ((const float4*)bias)[lane];
  float v0 = fmaxf(self.x + ((b0.x + b1.x) + (b2.x + b3.x)) +
                   ((b4.x + b5.x) + (b6.x + b7.x)) + bv.x, 0.f);
  float v1 = fmaxf(self.y + ((b0.y + b1.y) + (b2.y + b3.y)) +
                   ((b4.y + b5.y) + (b6.y + b7.y)) + bv.y, 0.f);
  float v2 = fmaxf(self.z + ((b0.z + b1.z) + (b2.z + b3.z)) +
                   ((b4.z + b5.z) + (b6.z + b7.z)) + bv.z, 0.f);
  float v3 = fmaxf(self.w + ((b0.w + b1.w) + (b2.w + b3.w)) +
                   ((b4.w + b5.w) + (b6.w + b7.w)) + bv.w, 0.f);
  *(float4*)(stnext + (size_t)row * D + lane * 4) = make_float4(v0, v1, v2, v3);
  ushort h0 = bf16_rn(v0), h1 = bf16_rn(v1), h2 = bf16_rn(v2), h3 = bf16_rn(v3);
  size_t ca = a_addr(row, lane * 4);
  *(ushort4*)&NAh[ca] = make_ushort4(h0, h1, h2, h3);
  *(ushort4*)&NAl[ca] = make_ushort4(
      bf16_rn(v0 - bf16_f(h0)), bf16_rn(v1 - bf16_f(h1)),
      bf16_rn(v2 - bf16_f(h2)), bf16_rn(v3 - bf16_f(h3)));
}

// ---------------------------------------------------------------------------
// k_pi: LINEAR reformulation, 512 threads/block (8 waves).  (validated R6/R7)
// ---------------------------------------------------------------------------
#define PI_LDS_BYTES (TCAP * 64 * 4 + 16 * 64 * 4 + 16 * 64 * 4 + 256 * 4 + \
                      3 * TCAP * 4 + 17 * 4 + 16 * 4 + 256 * 4)
__global__ __launch_bounds__(512) void k_pi(
    const float* __restrict__ states, float* __restrict__ out,
    const int* __restrict__ variants,
    const int* __restrict__ entP, const int* __restrict__ entPrev,
    const int* __restrict__ entDm, const int* __restrict__ offsG,
    const int* __restrict__ kidxG, const int* __restrict__ tlG,
    const int* __restrict__ cmatG, const int* __restrict__ lastPG,
    const int* __restrict__ lastIG, const int* __restrict__ lastMG,
    const int* __restrict__ cntG) {
  extern __shared__ __align__(16) float smf[];
  float* catb = smf;                       // [TCAP][64]  (becomes pref)
  float* S_lds = catb + TCAP * 64;         // [16][64]
  float* aS = S_lds + 16 * 64;             // [16][64] per-step sums
  float* cmatf = aS + 16 * 64;             // [256]
  int* eP  = (int*)(cmatf + 256);          // [TCAP]
  int* ePr = eP + TCAP;
  int* eDm = ePr + TCAP;
  int* offs = eDm + TCAP;                  // [17]
  int* kidx = offs + 17;                   // [16]
  int* tl = kidx + 16;                     // [256]
  int v = blockIdx.x / 12, cgi = blockIdx.x % 12;
  int grp = cgi >> 2;
  int tid = threadIdx.x, lane = tid & 63, w = tid >> 6;   // w in 0..7
  int cl = (cgi & 3) * 64 + lane;          // 0..255 within third
  int col = cgi * 64 + lane;               // 0..767

  int T = cntG[v * 2 + 0], U = cntG[v * 2 + 1];
  for (int x = tid; x < T; x += 512) {
    eP[x] = entP[v * TCAP + x];
    ePr[x] = entPrev[v * TCAP + x];
    eDm[x] = entDm[v * TCAP + x];
  }
  for (int x = tid; x < 17; x += 512) offs[x] = offsG[v * 17 + x];
  if (tid < 16) kidx[tid] = kidxG[v * 16 + tid];
  for (int x = tid; x < 256; x += 512) {
    tl[x] = tlG[v * 256 + x];
    cmatf[x] = (float)cmatG[v * 256 + x];
  }
  __syncthreads();

  // cat fill: 8 waves split the entries of each step
  for (int i = 0; i < L; i++) {
    int kk = kidx[i]; if (kk > NSTATE - 1) kk = NSTATE - 1;
    const float* embS = states + (size_t)kk * N * D;
    int o0 = offs[i], o1 = offs[i + 1];
    if (grp == 0) {
      for (int e = o0 + w; e < o1; e += 8)
        catb[e * 64 + lane] = embS[(size_t)eP[e] * D + cl];
    } else if (grp == 1) {
      float embA = embS[(size_t)variants[v * L + i] * D + cl];
      for (int e = o0 + w; e < o1; e += 8) catb[e * 64 + lane] = embA;
    } else {
      for (int e = o0 + w; e < o1; e += 8) {
        float sa = 0.f;
        int bm = eDm[e];
        while (bm) {
          int q = __ffs(bm) - 1; bm &= bm - 1;
          sa += embS[(size_t)tl[i * 16 + q] * D + cl];
        }
        catb[e * 64 + lane] = sa;
      }
    }
  }
  __syncthreads();
  // prefix over place-chains, chains distributed across 8 waves
  for (int u = w; u < U; u += 8) {
    int li = lastIG[v * TCAP + u];
    int len = 0;
    for (int c2 = li; c2 >= 0; c2 = ePr[c2]) len++;
    for (int j = 1; j < len; j++) {        // root -> last order
      int c2 = li;
      for (int k = 0; k < len - 1 - j; k++) c2 = ePr[c2];
      catb[c2 * 64 + lane] += catb[ePr[c2] * 64 + lane];
    }
  }
  __syncthreads();
  // per-step sums of pref
  for (int i = w; i < 16; i += 8) {
    float a = 0.f;
    for (int e = offs[i]; e < offs[i + 1]; e++) a += catb[e * 64 + lane];
    aS[i * 64 + lane] = a;
  }
  __syncthreads();
  // S recurrence (serial over 16 steps, wave 0)
  if (w == 0) {
    float S[16];
    float Sp = 0.f;
#pragma unroll
    for (int i = 0; i < 16; i++) {
      float sv = Sp + aS[i * 64 + lane];
#pragma unroll
      for (int j = 0; j < 16; j++)
        if (j < i) sv += cmatf[i * 16 + j] * S[j];
      S[i] = sv;
      S_lds[i * 64 + lane] = sv;
      Sp = sv;
    }
  }
  __syncthreads();
  // outputs, places distributed across 8 waves
  for (int u = w; u < U; u += 8) {
    int p = lastPG[v * TCAP + u];
    int li = lastIG[v * TCAP + u];
    int m = lastMG[v * TCAP + u];
    float acc = catb[li * 64 + lane];
    while (m) {
      int q = __ffs(m) - 1; m &= m - 1;
      acc += S_lds[q * 64 + lane];
    }
    atomicAdd(&out[(size_t)p * C + col], acc);
  }
}

// ---------------------------------------------------------------------------
extern "C" void kernel_launch(void* const* d_in, const int* in_sizes, int n_in,
                              void* d_out, int out_size, void* d_ws, size_t ws_size,
                              hipStream_t stream) {
  const float* emb      = (const float*)d_in[0];
  const float* Ws       = (const float*)d_in[1];
  const float* Wn       = (const float*)d_in[2];
  const float* bias     = (const float*)d_in[3];
  const int*   variants = (const int*)d_in[4];
  const int*   adj      = (const int*)d_in[5];
  const int*   ei       = (const int*)d_in[6];
  const int    E        = in_sizes[6] / 2;
  float* out            = (float*)d_out;

  char* base = (char*)d_ws;
  float* states = (float*)base;            base += (size_t)NSTATE * N * D * 4;
  float* Z      = (float*)base;            base += (size_t)N * 512 * 4;
  ushort* WtHi  = (ushort*)base;           base += (size_t)512 * 256 * 2;
  ushort* WtLo  = (ushort*)base;           base += (size_t)512 * 256 * 2;
  ushort* A0h   = (ushort*)base;           base += (size_t)N * D * 2;
  ushort* A0l   = (ushort*)base;           base += (size_t)N * D * 2;
  ushort* A1h   = (ushort*)base;           base += (size_t)N * D * 2;
  ushort* A1l   = (ushort*)base;           base += (size_t)N * D * 2;
  int* row_ptr  = (int*)base;              base += (N + 1) * 4;
  int* fillpos  = (int*)base;              base += N * 4;
  int* csr_src  = (int*)base;              base += (size_t)E * 4;
  int* stepP    = (int*)base;              base += V * L * FCAP * 4;
  int* stepDm   = (int*)base;              base += V * L * FCAP * 4;
  int* stepCnt  = (int*)base;              base += V * L * 4;
  int* hasG     = (int*)base;              base += V * L * 4;
  int* entP     = (int*)base;              base += V * TCAP * 4;
  int* entPrev  = (int*)base;              base += V * TCAP * 4;
  int* entDm    = (int*)base;              base += V * TCAP * 4;
  int* offsG    = (int*)base;              base += V * 17 * 4;
  int* kidxG    = (int*)base;              base += V * 16 * 4;
  int* tlG      = (int*)base;              base += V * 256 * 4;
  int* cmatG    = (int*)base;              base += V * 256 * 4;
  int* lastPG   = (int*)base;              base += V * TCAP * 4;
  int* lastIG   = (int*)base;              base += V * TCAP * 4;
  int* lastMG   = (int*)base;              base += V * TCAP * 4;
  int* cntG     = (int*)base;              base += V * 2 * 4;

  hipFuncSetAttribute((const void*)k_pi,
                      hipFuncAttributeMaxDynamicSharedMemorySize, PI_LDS_BYTES);

  k_init<<<545, 256, 0, stream>>>(emb, Ws, Wn, states, WtHi, WtLo, A0h, A0l,
                                  out, adj, variants, stepP, stepDm, stepCnt,
                                  hasG, tlG, ei, E, fillpos, row_ptr);
  // s = 0: GEMM fused with csr scatter-fill + metaB
  k_gemm0<<<dim3(64, 19), 256, 0, stream>>>(
      A0h, A0l, WtHi, WtLo, Z, ei, E, fillpos, csr_src, stepP, stepDm,
      stepCnt, hasG, entP, entPrev, entDm, offsG, kidxG, cmatG, lastPG,
      lastIG, lastMG, cntG);
  k_comb<<<N / 4, 256, 0, stream>>>(Z, bias, row_ptr, csr_src,
                                    states + (size_t)1 * N * D, A1h, A1l);

  ushort* AH[2] = {A0h, A1h};
  ushort* AL[2] = {A0l, A1l};
  for (int s = 1; s < NAPP; s++) {
    int cur = s & 1, nxt = cur ^ 1;
    k_gemm<<<dim3(64, 16), 256, 0, stream>>>(AH[cur], AL[cur], WtHi, WtLo, Z);
    k_comb<<<N / 4, 256, 0, stream>>>(Z, bias, row_ptr, csr_src,
                                      states + (size_t)(s + 1) * N * D,
                                      AH[nxt], AL[nxt]);
  }
  k_pi<<<V * 12, 512, PI_LDS_BYTES, stream>>>(states, out, variants, entP,
                                              entPrev, entDm, offsG, kidxG, tlG,
                                              cmatG, lastPG, lastIG, lastMG,
                                              cntG);
}

// Round 9
// 333.651 us; speedup vs baseline: 1.2485x; 1.0024x over previous
//
#include <hip/hip_runtime.h>

// Problem constants (fixed by the reference)
#define N 2048
#define D 256
#define C 768          // 3*D
#define V 2
#define L 16
#define NSTATE 15      // S_0..S_14 (step-15 mask provably empty)
#define NAPP 14        // encoder applications
#define TCAP 256       // canonical masked-entry cap per variant (expected ~107)
#define FCAP 64        // follower cap per step (expected ~32)

typedef __attribute__((ext_vector_type(8))) short bf16x8;
typedef __attribute__((ext_vector_type(4))) float f32x4;

__device__ __forceinline__ ushort bf16_rn(float x) {
  unsigned u = __float_as_uint(x);
  u += 0x7FFFu + ((u >> 16) & 1u);
  return (ushort)(u >> 16);
}
__device__ __forceinline__ float bf16_f(ushort h) {
  return __uint_as_float(((unsigned)h) << 16);
}

// Chunk-tiled operand layouts (chunk = 32 rows x 64 k = 2048 ushorts = 4 KB).
__device__ __forceinline__ size_t a_addr(int row, int k) {
  return ((size_t)(row >> 5) * 4 + (k >> 6)) * 2048 + (row & 31) * 64 + (k & 63);
}
__device__ __forceinline__ size_t wt_addr(int n, int k) {
  return ((size_t)(n >> 5) * 4 + (k >> 6)) * 2048 + (n & 31) * 64 + (k & 63);
}

// ---------------------------------------------------------------------------
// k_init: blocks 0..511: A0 bf16 split; Wt split.  (states0 copy dropped --
// k_pi reads emb directly for state 0; out zeroing moved to k_gemm0 aux.)
// blocks 512..543: metaA.  block 544: edge histogram + exclusive scan ->
// row_ptr/fillpos (independent of other blocks; int4-vectorized loads).
// ---------------------------------------------------------------------------
__global__ __launch_bounds__(256) void k_init(
    const float* __restrict__ emb, const float* __restrict__ Ws,
    const float* __restrict__ Wn,
    ushort* __restrict__ WtHi, ushort* __restrict__ WtLo,
    ushort* __restrict__ A0hi, ushort* __restrict__ A0lo,
    const int* __restrict__ adj, const int* __restrict__ variants,
    int* __restrict__ stepP, int* __restrict__ stepDm,
    int* __restrict__ stepCnt, int* __restrict__ hasG, int* __restrict__ tlG,
    const int* __restrict__ ei, int E, int* __restrict__ fillpos,
    int* __restrict__ row_ptr) {
  __shared__ int tl_sh[16];
  __shared__ int foll[FCAP], fbits[FCAP];
  __shared__ int sh_tc, sh_fcnt, sh_ecnt;
  __shared__ int hist[N];            // 8 KB (scan block only)
  __shared__ int part[256];
  __shared__ int base[257];
  int t = threadIdx.x;
  if (blockIdx.x < 512) {
    size_t i = (size_t)blockIdx.x * 256 + t;
    const size_t stride = (size_t)512 * 256;
    for (size_t x = i; x < (size_t)N * D; x += stride) {
      float v = emb[x];
      ushort h = bf16_rn(v);
      ushort l = bf16_rn(v - bf16_f(h));
      size_t a = a_addr((int)(x >> 8), (int)(x & 255));
      A0hi[a] = h;
      A0lo[a] = l;
    }
    for (size_t x = i; x < (size_t)512 * 256; x += stride) {
      int n = (int)(x >> 8), k = (int)(x & 255);
      float v = (n < 256) ? Ws[(size_t)k * 256 + n]
                          : Wn[(size_t)k * 256 + (n - 256)];
      ushort h = bf16_rn(v);
      size_t a = wt_addr(n, k);
      WtHi[a] = h;
      WtLo[a] = bf16_rn(v - bf16_f(h));
    }
    return;
  }
  if (blockIdx.x < 544) {
    // ---- metaA ----
    int vi = blockIdx.x - 512;
    int v = vi / L, i = vi % L;
    int a = variants[vi];
    if (t == 0) {
      int cnt = 0;
      for (int j = i + 1; j < L; j++) {
        int x = variants[v * L + j];
        bool dup = false;
        for (int q = 0; q < cnt; q++) if (tl_sh[q] == x) dup = true;
        if (!dup) tl_sh[cnt++] = x;
      }
      sh_tc = cnt;
      sh_fcnt = 0;
      sh_ecnt = 0;
      for (int q = 0; q < cnt; q++) tlG[vi * 16 + q] = tl_sh[q];
    }
    __syncthreads();
    for (int p = t; p < N; p += 256) {
      if (adj[(size_t)a * N + p] != 0) {
        int f = atomicAdd(&sh_fcnt, 1);
        if (f < FCAP) foll[f] = p;
      }
    }
    __syncthreads();
    int fc = sh_fcnt < FCAP ? sh_fcnt : FCAP;
    int tc = sh_tc;
    for (int x = t; x < fc; x += 256) fbits[x] = 0;
    __syncthreads();
    for (int x = t; x < fc * tc; x += 256) {
      int fi = x / tc, q = x - fi * tc;
      if (adj[(size_t)foll[fi] * N + tl_sh[q]] != 0) atomicOr(&fbits[fi], 1 << q);
    }
    __syncthreads();
    for (int fi = t; fi < fc; fi += 256) {
      int bits = fbits[fi];
      if (bits) {
        int e = atomicAdd(&sh_ecnt, 1);
        stepP[vi * FCAP + e] = foll[fi];
        stepDm[vi * FCAP + e] = bits;
      }
    }
    __syncthreads();
    if (t == 0) {
      stepCnt[vi] = sh_ecnt;
      hasG[vi] = (sh_fcnt > 0);
    }
    return;
  }
  // ---- scan block (no dependency on other blocks of this kernel) ----
  for (int p = t; p < N; p += 256) hist[p] = 0;
  __syncthreads();
  {
    const int e4 = E >> 2;
    const int4* dsts = (const int4*)(ei + E);
    for (int g = t; g < e4; g += 256) {
      int4 d = dsts[g];
      atomicAdd(&hist[d.x], 1);
      atomicAdd(&hist[d.y], 1);
      atomicAdd(&hist[d.z], 1);
      atomicAdd(&hist[d.w], 1);
    }
    for (int e = (e4 << 2) + t; e < E; e += 256) atomicAdd(&hist[ei[E + e]], 1);
  }
  __syncthreads();
  int vv[8];
  int s = 0;
  for (int j = 0; j < 8; j++) { vv[j] = hist[t * 8 + j]; s += vv[j]; }
  part[t] = s;
  __syncthreads();
  if (t == 0) {
    int acc = 0;
    for (int q = 0; q < 256; q++) { base[q] = acc; acc += part[q]; }
    base[256] = acc;
  }
  __syncthreads();
  int acc = base[t];
  for (int j = 0; j < 8; j++) {
    row_ptr[t * 8 + j] = acc;
    fillpos[t * 8 + j] = acc;
    acc += vv[j];
  }
  if (t == 255) row_ptr[N] = base[256];
}

// ---------------------------------------------------------------------------
// gemm_body: Z = A @ [W_self|W_nbr] (M=2048,K=256,N=512), bf16 3-product
// split, fp32 accum, LDS double-buffered.  (R4-validated schedule, verbatim;
// LDS carved from a raw 36.9 KB buffer so k_gemm0 can reuse it.)
// ---------------------------------------------------------------------------
__device__ __forceinline__ void gemm_body(
    const ushort* __restrict__ Ah, const ushort* __restrict__ Al,
    const ushort* __restrict__ Wh_g, const ushort* __restrict__ Wl_g,
    float* __restrict__ Z, ushort* smem, const int mb, const int nb,
    const int tid) {
  ushort (*Ash)[32][72] = (ushort (*)[32][72])(smem);
  ushort (*Asl)[32][72] = (ushort (*)[32][72])(smem + 4608);
  ushort (*Wsh)[32][72] = (ushort (*)[32][72])(smem + 9216);
  ushort (*Wsl)[32][72] = (ushort (*)[32][72])(smem + 13824);
  const int wave = tid >> 6, lane = tid & 63;
  const int quad = lane >> 4, l16 = lane & 15;
  const int wr = wave >> 1, wc = wave & 1;
  const int sr = tid >> 3, sc = (tid & 7) * 8;

  f32x4 acc = {0.f, 0.f, 0.f, 0.f};
  size_t abase = (size_t)mb * 4 * 2048 + (size_t)tid * 8;
  size_t wbase = (size_t)nb * 4 * 2048 + (size_t)tid * 8;
  {
    uint4 ra  = *(const uint4*)&Ah[abase];
    uint4 rl  = *(const uint4*)&Al[abase];
    uint4 rwh = *(const uint4*)&Wh_g[wbase];
    uint4 rwl = *(const uint4*)&Wl_g[wbase];
    *(uint4*)&Ash[0][sr][sc] = ra;
    *(uint4*)&Asl[0][sr][sc] = rl;
    *(uint4*)&Wsh[0][sr][sc] = rwh;
    *(uint4*)&Wsl[0][sr][sc] = rwl;
  }
  __syncthreads();
#pragma unroll
  for (int c = 0; c < 4; c++) {
    const int rb = c & 1;
    uint4 ra, rl, rwh, rwl;
    if (c < 3) {
      size_t o = (size_t)(c + 1) * 2048;
      ra  = *(const uint4*)&Ah[abase + o];
      rl  = *(const uint4*)&Al[abase + o];
      rwh = *(const uint4*)&Wh_g[wbase + o];
      rwl = *(const uint4*)&Wl_g[wbase + o];
    }
#pragma unroll
    for (int kf = 0; kf < 2; kf++) {
      int ko = kf * 32 + quad * 8;
      bf16x8 a_h = *(const bf16x8*)&Ash[rb][wr * 16 + l16][ko];
      bf16x8 a_l = *(const bf16x8*)&Asl[rb][wr * 16 + l16][ko];
      bf16x8 w_h = *(const bf16x8*)&Wsh[rb][wc * 16 + l16][ko];
      bf16x8 w_l = *(const bf16x8*)&Wsl[rb][wc * 16 + l16][ko];
      acc = __builtin_amdgcn_mfma_f32_16x16x32_bf16(a_h, w_h, acc, 0, 0, 0);
      acc = __builtin_amdgcn_mfma_f32_16x16x32_bf16(a_h, w_l, acc, 0, 0, 0);
      acc = __builtin_amdgcn_mfma_f32_16x16x32_bf16(a_l, w_h, acc, 0, 0, 0);
    }
    if (c < 3) {
      const int wb = rb ^ 1;
      *(uint4*)&Ash[wb][sr][sc] = ra;
      *(uint4*)&Asl[wb][sr][sc] = rl;
      *(uint4*)&Wsh[wb][sr][sc] = rwh;
      *(uint4*)&Wsl[wb][sr][sc] = rwl;
      __syncthreads();
    }
  }
  int col = nb * 32 + wc * 16 + l16;
  int row0 = mb * 32 + wr * 16 + quad * 4;
#pragma unroll
  for (int r = 0; r < 4; r++)
    Z[(size_t)(row0 + r) * 512 + col] = acc[r];
}

// ---------------------------------------------------------------------------
// k_gemm: plain GEMM iteration (s = 1..13).
// ---------------------------------------------------------------------------
__global__ __launch_bounds__(256) void k_gemm(
    const ushort* __restrict__ Ah, const ushort* __restrict__ Al,
    const ushort* __restrict__ Wh_g, const ushort* __restrict__ Wl_g,
    float* __restrict__ Z) {
  __shared__ __align__(16) ushort smem[18432];   // 36.9 KB
  gemm_body(Ah, Al, Wh_g, Wl_g, Z, smem, blockIdx.x, blockIdx.y, threadIdx.x);
}

// ---------------------------------------------------------------------------
// k_gemm0: s=0 GEMM (nb<16) fused with csr scatter-fill (aux 0..127),
// metaB (aux 128..129), and out-zeroing (aux 130..191; out consumed only by
// k_pi which runs later).  Aux LDS carved from the same buffer.
// ---------------------------------------------------------------------------
__global__ __launch_bounds__(256) void k_gemm0(
    const ushort* __restrict__ Ah, const ushort* __restrict__ Al,
    const ushort* __restrict__ Wh_g, const ushort* __restrict__ Wl_g,
    float* __restrict__ Z,
    const int* __restrict__ ei, int E, int* __restrict__ fillpos,
    int* __restrict__ csr_src,
    const int* __restrict__ stepP, const int* __restrict__ stepDm,
    const int* __restrict__ stepCnt, const int* __restrict__ hasG,
    int* __restrict__ entP, int* __restrict__ entPrev, int* __restrict__ entDm,
    int* __restrict__ offsG, int* __restrict__ kidxG, int* __restrict__ cmatG,
    int* __restrict__ lastPG, int* __restrict__ lastIG, int* __restrict__ lastMG,
    int* __restrict__ cntG, float* __restrict__ out) {
  __shared__ __align__(16) ushort smem[18432];   // 36.9 KB
  int t = threadIdx.x;
  if (blockIdx.y < 16) {
    gemm_body(Ah, Al, Wh_g, Wl_g, Z, smem, blockIdx.x, blockIdx.y, t);
    return;
  }
  int aux = (blockIdx.y - 16) * 64 + blockIdx.x;   // 0..191
  if (aux < 128) {
    for (int e = aux * 256 + t; e < E; e += 128 * 256) {
      int dst = ei[E + e];
      int pos = atomicAdd(&fillpos[dst], 1);
      csr_src[pos] = ei[e];
    }
    return;
  }
  if (aux >= 130) {   // out-zeroing: 62 blocks over N*C/4 float4s
    float4* o4 = (float4*)out;
    const int tot = N * C / 4;
    for (int x = (aux - 130) * 256 + t; x < tot; x += 62 * 256)
      o4[x] = make_float4(0.f, 0.f, 0.f, 0.f);
    return;
  }
  int vb = aux - 128;
  // metaB LDS carve (17.5 KB of the 36.9 KB buffer)
  int* pmask = (int*)smem;                         // [N]
  int (*sP)[FCAP] = (int (*)[FCAP])(pmask + N);    // [16][FCAP]
  int (*sDm)[FCAP] = (int (*)[FCAP])((int*)sP + 16 * FCAP);
  int* cnt = (int*)sDm + 16 * FCAP;                // [16]
  int* offs = cnt + 16;                            // [17]
  int* cmat_sh = offs + 17;                        // [256]
  int* sh_u = cmat_sh + 256;                       // [1]
  for (int p = t; p < N; p += 256) pmask[p] = 0;
  for (int x = t; x < 256; x += 256) cmat_sh[x] = 0;
  if (t < 16) cnt[t] = stepCnt[vb * L + t];
  if (t == 0) *sh_u = 0;
  __syncthreads();
  if (t == 0) {
    int acc = 0;
    for (int i = 0; i < 16; i++) {
      offs[i] = acc < TCAP ? acc : TCAP;
      acc += cnt[i];
    }
    offs[16] = acc < TCAP ? acc : TCAP;
    cntG[vb * 2 + 0] = offs[16];
    int k = 0;
    for (int i = 0; i < L; i++) {
      kidxG[vb * 16 + i] = k;
      if (hasG[vb * L + i]) k++;
    }
  }
  for (int x = t; x < 16 * FCAP; x += 256) {
    int i = x >> 6, f = x & 63;
    if (f < stepCnt[vb * L + i]) {
      int p = stepP[(vb * L + i) * FCAP + f];
      sP[i][f] = p;
      sDm[i][f] = stepDm[(vb * L + i) * FCAP + f];
      atomicOr(&pmask[p], 1 << i);
    }
  }
  __syncthreads();
  for (int x = t; x < 16 * FCAP; x += 256) {
    int i = x >> 6, f = x & 63;
    if (f < cnt[i]) {
      int e = offs[i] + f;
      if (e < TCAP) {
        int p = sP[i][f];
        entP[vb * TCAP + e] = p;
        entDm[vb * TCAP + e] = sDm[i][f];
        int m = pmask[p] & ((1 << i) - 1);
        int prev = -1;
        if (m) {
          int j = 31 - __clz(m);
          int cj = cnt[j];
          for (int f2 = 0; f2 < cj; f2++)
            if (sP[j][f2] == p) { prev = offs[j] + f2; break; }
        }
        entPrev[vb * TCAP + e] = prev;
      }
    }
  }
  __syncthreads();
  for (int p = t; p < N; p += 256) {
    int m = pmask[p];
    if (m) {
      int u = atomicAdd(sh_u, 1);
      int j = 31 - __clz(m);
      int li = -1;
      int cj = cnt[j];
      for (int f2 = 0; f2 < cj; f2++)
        if (sP[j][f2] == p) { li = offs[j] + f2; break; }
      lastPG[vb * TCAP + u] = p;
      lastIG[vb * TCAP + u] = li;
      lastMG[vb * TCAP + u] = m;
      int mm = m;
      while (mm) {
        int bi = __ffs(mm) - 1; mm &= mm - 1;
        int m2 = m & ((1 << bi) - 1);
        while (m2) {
          int bj = __ffs(m2) - 1; m2 &= m2 - 1;
          atomicAdd(&cmat_sh[bi * 16 + bj], 1);
        }
      }
    }
  }
  __syncthreads();
  if (t == 0) cntG[vb * 2 + 1] = *sh_u;
  for (int x = t; x < 256; x += 256) cmatG[vb * 256 + x] = cmat_sh[x];
  for (int x = t; x < 17; x += 256) offsG[vb * 17 + x] = offs[x];
}

// ---------------------------------------------------------------------------
// k_comb: next[r] = relu(Z1[r] + sum_{e in in(r)} Z2[src_e] + b).
// One wave per row; 8-deep gather (8 accumulators), 4-wide + scalar tail.
// (validated R8)
// ---------------------------------------------------------------------------
__global__ __launch_bounds__(256) void k_comb(
    const float* __restrict__ Z, const float* __restrict__ bias,
    const int* __restrict__ row_ptr, const int* __restrict__ csr_src,
    float* __restrict__ stnext, ushort* __restrict__ NAh,
    ushort* __restrict__ NAl) {
  int row = blockIdx.x * 4 + (threadIdx.x >> 6);
  int lane = threadIdx.x & 63;
  const float4* Zp = (const float4*)Z;
  float4 self = Zp[(size_t)row * 128 + lane];            // Z1 self
  float4 b0 = {0.f, 0.f, 0.f, 0.f}, b1 = b0, b2 = b0, b3 = b0;
  float4 b4 = b0, b5 = b0, b6 = b0, b7 = b0;
  int e0 = row_ptr[row], e1 = row_ptr[row + 1];
  int e = e0;
  for (; e + 7 < e1; e += 8) {
    int s0 = csr_src[e],     s1 = csr_src[e + 1];
    int s2 = csr_src[e + 2], s3 = csr_src[e + 3];
    int s4 = csr_src[e + 4], s5 = csr_src[e + 5];
    int s6 = csr_src[e + 6], s7 = csr_src[e + 7];
    float4 x0 = Zp[(size_t)s0 * 128 + 64 + lane];
    float4 x1 = Zp[(size_t)s1 * 128 + 64 + lane];
    float4 x2 = Zp[(size_t)s2 * 128 + 64 + lane];
    float4 x3 = Zp[(size_t)s3 * 128 + 64 + lane];
    float4 x4 = Zp[(size_t)s4 * 128 + 64 + lane];
    float4 x5 = Zp[(size_t)s5 * 128 + 64 + lane];
    float4 x6 = Zp[(size_t)s6 * 128 + 64 + lane];
    float4 x7 = Zp[(size_t)s7 * 128 + 64 + lane];
    b0.x += x0.x; b0.y += x0.y; b0.z += x0.z; b0.w += x0.w;
    b1.x += x1.x; b1.y += x1.y; b1.z += x1.z; b1.w += x1.w;
    b2.x += x2.x; b2.y += x2.y; b2.z += x2.z; b2.w += x2.w;
    b3.x += x3.x; b3.y += x3.y; b3.z += x3.z; b3.w += x3.w;
    b4.x += x4.x; b4.y += x4.y; b4.z += x4.z; b4.w += x4.w;
    b5.x += x5.x; b5.y += x5.y; b5.z += x5.z; b5.w += x5.w;
    b6.x += x6.x; b6.y += x6.y; b6.z += x6.z; b6.w += x6.w;
    b7.x += x7.x; b7.y += x7.y; b7.z += x7.z; b7.w += x7.w;
  }
  if (e + 3 < e1) {
    int s0 = csr_src[e],     s1 = csr_src[e + 1];
    int s2 = csr_src[e + 2], s3 = csr_src[e + 3];
    float4 x0 = Zp[(size_t)s0 * 128 + 64 + lane];
    float4 x1 = Zp[(size_t)s1 * 128 + 64 + lane];
    float4 x2 = Zp[(size_t)s2 * 128 + 64 + lane];
    float4 x3 = Zp[(size_t)s3 * 128 + 64 + lane];
    b0.x += x0.x; b0.y += x0.y; b0.z += x0.z; b0.w += x0.w;
    b1.x += x1.x; b1.y += x1.y; b1.z += x1.z; b1.w += x1.w;
    b2.x += x2.x; b2.y += x2.y; b2.z += x2.z; b2.w += x2.w;
    b3.x += x3.x; b3.y += x3.y; b3.z += x3.z; b3.w += x3.w;
    e += 4;
  }
  for (; e < e1; e++) {
    float4 x0 = Zp[(size_t)csr_src[e] * 128 + 64 + lane];
    b0.x += x0.x; b0.y += x0.y; b0.z += x0.z; b0.w += x0.w;
  }
  float4 bv = ((const float4*)bias)[lane];
  float v0 = fmaxf(self.x + ((b0.x + b1.x) + (b2.x + b3.x)) +
                   ((b4.x + b5.x) + (b6.x + b7.x)) + bv.x, 0.f);
  float v1 = fmaxf(self.y + ((b0.y + b1.y) + (b2.y + b3.y)) +
                   ((b4.y + b5.y) + (b6.y + b7.y)) + bv.y, 0.f);
  float v2 = fmaxf(self.z + ((b0.z + b1.z) + (b2.z + b3.z)) +
                   ((b4.z + b5.z) + (b6.z + b7.z)) + bv.z, 0.f);
  float v3 = fmaxf(self.w + ((b0.w + b1.w) + (b2.w + b3.w)) +
                   ((b4.w + b5.w) + (b6.w + b7.w)) + bv.w, 0.f);
  *(float4*)(stnext + (size_t)row * D + lane * 4) = make_float4(v0, v1, v2, v3);
  ushort h0 = bf16_rn(v0), h1 = bf16_rn(v1), h2 = bf16_rn(v2), h3 = bf16_rn(v3);
  size_t ca = a_addr(row, lane * 4);
  *(ushort4*)&NAh[ca] = make_ushort4(h0, h1, h2, h3);
  *(ushort4*)&NAl[ca] = make_ushort4(
      bf16_rn(v0 - bf16_f(h0)), bf16_rn(v1 - bf16_f(h1)),
      bf16_rn(v2 - bf16_f(h2)), bf16_rn(v3 - bf16_f(h3)));
}

// ---------------------------------------------------------------------------
// k_pi: LINEAR reformulation, 512 threads/block (8 waves).  State 0 now
// read directly from emb (states slot 0 unused).  (validated R6-R8)
// ---------------------------------------------------------------------------
#define PI_LDS_BYTES (TCAP * 64 * 4 + 16 * 64 * 4 + 16 * 64 * 4 + 256 * 4 + \
                      3 * TCAP * 4 + 17 * 4 + 16 * 4 + 256 * 4)
__global__ __launch_bounds__(512) void k_pi(
    const float* __restrict__ emb, const float* __restrict__ states,
    float* __restrict__ out,
    const int* __restrict__ variants,
    const int* __restrict__ entP, const int* __restrict__ entPrev,
    const int* __restrict__ entDm, const int* __restrict__ offsG,
    const int* __restrict__ kidxG, const int* __restrict__ tlG,
    const int* __restrict__ cmatG, const int* __restrict__ lastPG,
    const int* __restrict__ lastIG, const int* __restrict__ lastMG,
    const int* __restrict__ cntG) {
  extern __shared__ __align__(16) float smf[];
  float* catb = smf;                       // [TCAP][64]  (becomes pref)
  float* S_lds = catb + TCAP * 64;         // [16][64]
  float* aS = S_lds + 16 * 64;             // [16][64] per-step sums
  float* cmatf = aS + 16 * 64;             // [256]
  int* eP  = (int*)(cmatf + 256);          // [TCAP]
  int* ePr = eP + TCAP;
  int* eDm = ePr + TCAP;
  int* offs = eDm + TCAP;                  // [17]
  int* kidx = offs + 17;                   // [16]
  int* tl = kidx + 16;                     // [256]
  int v = blockIdx.x / 12, cgi = blockIdx.x % 12;
  int grp = cgi >> 2;
  int tid = threadIdx.x, lane = tid & 63, w = tid >> 6;   // w in 0..7
  int cl = (cgi & 3) * 64 + lane;          // 0..255 within third
  int col = cgi * 64 + lane;               // 0..767

  int T = cntG[v * 2 + 0], U = cntG[v * 2 + 1];
  for (int x = tid; x < T; x += 512) {
    eP[x] = entP[v * TCAP + x];
    ePr[x] = entPrev[v * TCAP + x];
    eDm[x] = entDm[v * TCAP + x];
  }
  for (int x = tid; x < 17; x += 512) offs[x] = offsG[v * 17 + x];
  if (tid < 16) kidx[tid] = kidxG[v * 16 + tid];
  for (int x = tid; x < 256; x += 512) {
    tl[x] = tlG[v * 256 + x];
    cmatf[x] = (float)cmatG[v * 256 + x];
  }
  __syncthreads();

  // cat fill: 8 waves split the entries of each step
  for (int i = 0; i < L; i++) {
    int kk = kidx[i]; if (kk > NSTATE - 1) kk = NSTATE - 1;
    const float* embS = kk ? (states + (size_t)kk * N * D) : emb;
    int o0 = offs[i], o1 = offs[i + 1];
    if (grp == 0) {
      for (int e = o0 + w; e < o1; e += 8)
        catb[e * 64 + lane] = embS[(size_t)eP[e] * D + cl];
    } else if (grp == 1) {
      float embA = embS[(size_t)variants[v * L + i] * D + cl];
      for (int e = o0 + w; e < o1; e += 8) catb[e * 64 + lane] = embA;
    } else {
      for (int e = o0 + w; e < o1; e += 8) {
        float sa = 0.f;
        int bm = eDm[e];
        while (bm) {
          int q = __ffs(bm) - 1; bm &= bm - 1;
          sa += embS[(size_t)tl[i * 16 + q] * D + cl];
        }
        catb[e * 64 + lane] = sa;
      }
    }
  }
  __syncthreads();
  // prefix over place-chains, chains distributed across 8 waves
  for (int u = w; u < U; u += 8) {
    int li = lastIG[v * TCAP + u];
    int len = 0;
    for (int c2 = li; c2 >= 0; c2 = ePr[c2]) len++;
    for (int j = 1; j < len; j++) {        // root -> last order
      int c2 = li;
      for (int k = 0; k < len - 1 - j; k++) c2 = ePr[c2];
      catb[c2 * 64 + lane] += catb[ePr[c2] * 64 + lane];
    }
  }
  __syncthreads();
  // per-step sums of pref
  for (int i = w; i < 16; i += 8) {
    float a = 0.f;
    for (int e = offs[i]; e < offs[i + 1]; e++) a += catb[e * 64 + lane];
    aS[i * 64 + lane] = a;
  }
  __syncthreads();
  // S recurrence (serial over 16 steps, wave 0)
  if (w == 0) {
    float S[16];
    float Sp = 0.f;
#pragma unroll
    for (int i = 0; i < 16; i++) {
      float sv = Sp + aS[i * 64 + lane];
#pragma unroll
      for (int j = 0; j < 16; j++)
        if (j < i) sv += cmatf[i * 16 + j] * S[j];
      S[i] = sv;
      S_lds[i * 64 + lane] = sv;
      Sp = sv;
    }
  }
  __syncthreads();
  // outputs, places distributed across 8 waves
  for (int u = w; u < U; u += 8) {
    int p = lastPG[v * TCAP + u];
    int li = lastIG[v * TCAP + u];
    int m = lastMG[v * TCAP + u];
    float acc = catb[li * 64 + lane];
    while (m) {
      int q = __ffs(m) - 1; m &= m - 1;
      acc += S_lds[q * 64 + lane];
    }
    atomicAdd(&out[(size_t)p * C + col], acc);
  }
}

// ---------------------------------------------------------------------------
extern "C" void kernel_launch(void* const* d_in, const int* in_sizes, int n_in,
                              void* d_out, int out_size, void* d_ws, size_t ws_size,
                              hipStream_t stream) {
  const float* emb      = (const float*)d_in[0];
  const float* Ws       = (const float*)d_in[1];
  const float* Wn       = (const float*)d_in[2];
  const float* bias     = (const float*)d_in[3];
  const int*   variants = (const int*)d_in[4];
  const int*   adj      = (const int*)d_in[5];
  const int*   ei       = (const int*)d_in[6];
  const int    E        = in_sizes[6] / 2;
  float* out            = (float*)d_out;

  char* base = (char*)d_ws;
  float* states = (float*)base;            base += (size_t)NSTATE * N * D * 4;
  float* Z      = (float*)base;            base += (size_t)N * 512 * 4;
  ushort* WtHi  = (ushort*)base;           base += (size_t)512 * 256 * 2;
  ushort* WtLo  = (ushort*)base;           base += (size_t)512 * 256 * 2;
  ushort* A0h   = (ushort*)base;           base += (size_t)N * D * 2;
  ushort* A0l   = (ushort*)base;           base += (size_t)N * D * 2;
  ushort* A1h   = (ushort*)base;           base += (size_t)N * D * 2;
  ushort* A1l   = (ushort*)base;           base += (size_t)N * D * 2;
  int* row_ptr  = (int*)base;              base += (N + 1) * 4;
  int* fillpos  = (int*)base;              base += N * 4;
  int* csr_src  = (int*)base;              base += (size_t)E * 4;
  int* stepP    = (int*)base;              base += V * L * FCAP * 4;
  int* stepDm   = (int*)base;              base += V * L * FCAP * 4;
  int* stepCnt  = (int*)base;              base += V * L * 4;
  int* hasG     = (int*)base;              base += V * L * 4;
  int* entP     = (int*)base;              base += V * TCAP * 4;
  int* entPrev  = (int*)base;              base += V * TCAP * 4;
  int* entDm    = (int*)base;              base += V * TCAP * 4;
  int* offsG    = (int*)base;              base += V * 17 * 4;
  int* kidxG    = (int*)base;              base += V * 16 * 4;
  int* tlG      = (int*)base;              base += V * 256 * 4;
  int* cmatG    = (int*)base;              base += V * 256 * 4;
  int* lastPG   = (int*)base;              base += V * TCAP * 4;
  int* lastIG   = (int*)base;              base += V * TCAP * 4;
  int* lastMG   = (int*)base;              base += V * TCAP * 4;
  int* cntG     = (int*)base;              base += V * 2 * 4;

  hipFuncSetAttribute((const void*)k_pi,
                      hipFuncAttributeMaxDynamicSharedMemorySize, PI_LDS_BYTES);

  k_init<<<545, 256, 0, stream>>>(emb, Ws, Wn, WtHi, WtLo, A0h, A0l,
                                  adj, variants, stepP, stepDm, stepCnt,
                                  hasG, tlG, ei, E, fillpos, row_ptr);
  // s = 0: GEMM fused with csr scatter-fill + metaB + out-zeroing
  k_gemm0<<<dim3(64, 19), 256, 0, stream>>>(
      A0h, A0l, WtHi, WtLo, Z, ei, E, fillpos, csr_src, stepP, stepDm,
      stepCnt, hasG, entP, entPrev, entDm, offsG, kidxG, cmatG, lastPG,
      lastIG, lastMG, cntG, out);
  k_comb<<<N / 4, 256, 0, stream>>>(Z, bias, row_ptr, csr_src,
                                    states + (size_t)1 * N * D, A1h, A1l);

  ushort* AH[2] = {A0h, A1h};
  ushort* AL[2] = {A0l, A1l};
  for (int s = 1; s < NAPP; s++) {
    int cur = s & 1, nxt = cur ^ 1;
    k_gemm<<<dim3(64, 16), 256, 0, stream>>>(AH[cur], AL[cur], WtHi, WtLo, Z);
    k_comb<<<N / 4, 256, 0, stream>>>(Z, bias, row_ptr, csr_src,
                                      states + (size_t)(s + 1) * N * D,
                                      AH[nxt], AL[nxt]);
  }
  k_pi<<<V * 12, 512, PI_LDS_BYTES, stream>>>(emb, states, out, variants, entP,
                                              entPrev, entDm, offsG, kidxG, tlG,
                                              cmatG, lastPG, lastIG, lastMG,
                                              cntG);
}